// Round 1
// baseline (625.032 us; speedup 1.0000x reference)
//
#include <hip/hip_runtime.h>
#include <hip/hip_bf16.h>

typedef __bf16 bf16x8 __attribute__((ext_vector_type(8)));
typedef float f32x4 __attribute__((ext_vector_type(4)));
typedef unsigned int u32x4 __attribute__((ext_vector_type(4)));

#define MTOT    8192          // BATCH*SEQLEN
#define DMODEL  768
#define DINNER  1536
#define DSTATE  128
#define NHEADS  24
#define CONVDIM 1792
#define LDZ     3328          // z(1536)+xBC(1792); dt columns handled separately in fp32
#define SEQ     2048
#define CHUNK   128
#define NCHUNK  16
#define NBH     96            // BATCH*NHEADS

#define NU   (MTOT*DMODEL)    // 6291456
#define NWI  (LDZ*DMODEL)     // 2555904
#define NWO  (DMODEL*DINNER)  // 1179648

// ---------------- f32 -> bf16 conversions ----------------
__global__ __launch_bounds__(256) void cvt_bf16(const float* __restrict__ u, const float* __restrict__ Wi,
                                                const float* __restrict__ Wo,
                                                __hip_bfloat16* __restrict__ ub, __hip_bfloat16* __restrict__ wib,
                                                __hip_bfloat16* __restrict__ wob) {
  int i = blockIdx.x * 256 + threadIdx.x;
  if (i < NU) ub[i] = __float2bfloat16(u[i]);
  else if (i < NU + NWI) { int k = i - NU; wib[k] = __float2bfloat16(Wi[k]); }
  else if (i < NU + NWI + NWO) { int k = i - NU - NWI; wob[k] = __float2bfloat16(Wo[k]); }
}

// ---------------- bf16 NT GEMM: C[m][n] = sum_k A[m][k]*B[n][k] ----------------
// 128x128 tile, BK=32, 4 waves (2x2), 4x4 x (16x16x32) MFMA per wave. Reg-staged LDS.
__global__ __launch_bounds__(256, 2) void gemm_bt(const __hip_bfloat16* __restrict__ A,
                                                  const __hip_bfloat16* __restrict__ B,
                                                  float* __restrict__ C, int lda, int ldb, int ldc, int nk) {
  __shared__ __align__(16) __hip_bfloat16 As[128 * 40];  // +8 pad per row: conflict-friendly, 16B-aligned rows
  __shared__ __align__(16) __hip_bfloat16 Bs[128 * 40];
  const int tid = threadIdx.x;
  const int lane = tid & 63, wid = tid >> 6;
  const int wm = wid >> 1, wn = wid & 1;
  const int bm = blockIdx.y, bn = blockIdx.x;
  const int ra = tid >> 2, ka = tid & 3;  // stage: row 0..63 (+64), 16B chunk 0..3
  const __hip_bfloat16* Ag0 = A + (size_t)(bm * 128 + ra) * lda + ka * 8;
  const __hip_bfloat16* Ag1 = Ag0 + (size_t)64 * lda;
  const __hip_bfloat16* Bg0 = B + (size_t)(bn * 128 + ra) * ldb + ka * 8;
  const __hip_bfloat16* Bg1 = Bg0 + (size_t)64 * ldb;
  f32x4 acc[4][4] = {};
  u32x4 a0 = *(const u32x4*)Ag0, a1 = *(const u32x4*)Ag1;
  u32x4 b0 = *(const u32x4*)Bg0, b1 = *(const u32x4*)Bg1;
  const int lr = lane & 15, lk = lane >> 4;
  const int arow = wm * 64 + lr, brow = wn * 64 + lr;
  for (int ks = 0; ks < nk; ++ks) {
    __syncthreads();  // previous iteration's LDS reads done
    *(u32x4*)&As[ra * 40 + ka * 8] = a0;
    *(u32x4*)&As[(ra + 64) * 40 + ka * 8] = a1;
    *(u32x4*)&Bs[ra * 40 + ka * 8] = b0;
    *(u32x4*)&Bs[(ra + 64) * 40 + ka * 8] = b1;
    __syncthreads();
    if (ks + 1 < nk) {  // prefetch next K-step while MFMAs run
      a0 = *(const u32x4*)(Ag0 + (ks + 1) * 32);
      a1 = *(const u32x4*)(Ag1 + (ks + 1) * 32);
      b0 = *(const u32x4*)(Bg0 + (ks + 1) * 32);
      b1 = *(const u32x4*)(Bg1 + (ks + 1) * 32);
    }
    bf16x8 af[4], bfr[4];
#pragma unroll
    for (int i = 0; i < 4; ++i) {
      af[i] = *(const bf16x8*)&As[(arow + i * 16) * 40 + lk * 8];
      bfr[i] = *(const bf16x8*)&Bs[(brow + i * 16) * 40 + lk * 8];
    }
#pragma unroll
    for (int i = 0; i < 4; ++i)
#pragma unroll
      for (int j = 0; j < 4; ++j)
        acc[i][j] = __builtin_amdgcn_mfma_f32_16x16x32_bf16(af[i], bfr[j], acc[i][j], 0, 0, 0);
  }
  // C/D layout: col = lane&15, row = (lane>>4)*4 + reg
  const int crow0 = bm * 128 + wm * 64 + lk * 4;
  const int ccol0 = bn * 128 + wn * 64 + lr;
#pragma unroll
  for (int i = 0; i < 4; ++i)
#pragma unroll
    for (int j = 0; j < 4; ++j)
#pragma unroll
      for (int r = 0; r < 4; ++r)
        C[(size_t)(crow0 + i * 16 + r) * ldc + ccol0 + j * 16] = acc[i][j][r];
}

// ---------------- fp32 dt path: dt_raw = u . W_in[3328+h], softplus, dA=exp(dt*A) ----------------
__global__ __launch_bounds__(256) void dt_kernel(const float* __restrict__ u, const float* __restrict__ Wi,
                                                 const float* __restrict__ dtb, const float* __restrict__ alog,
                                                 float* __restrict__ dtS, float* __restrict__ dAb) {
  int m = blockIdx.x;
  __shared__ __align__(16) float ush[DMODEL];
  for (int i = threadIdx.x; i < DMODEL; i += 256) ush[i] = u[(size_t)m * DMODEL + i];
  __syncthreads();
  int tid = threadIdx.x;
  if (tid < 192) {
    int h = tid >> 3, j = tid & 7;  // 8 lanes per head
    const float4* w4 = (const float4*)(Wi + (size_t)(LDZ + h) * DMODEL + j * 96);
    const float4* u4 = (const float4*)(ush + j * 96);
    float s = 0.f;
#pragma unroll
    for (int k = 0; k < 24; ++k) {
      float4 a = u4[k], b = w4[k];
      s += a.x * b.x + a.y * b.y + a.z * b.z + a.w * b.w;
    }
    s += __shfl_xor(s, 1);
    s += __shfl_xor(s, 2);
    s += __shfl_xor(s, 4);
    if (j == 0) {
      float x = s + dtb[h];
      float dt = (x > 20.f) ? x : log1pf(expf(x));
      dtS[(size_t)m * NHEADS + h] = dt;
      dAb[(size_t)m * NHEADS + h] = expf(-expf(alog[h]) * dt);
    }
  }
}

// ---------------- depthwise causal conv(4) + SiLU ----------------
__global__ __launch_bounds__(256) void conv_silu(const float* __restrict__ zxb, const float* __restrict__ cw,
                                                 const float* __restrict__ cb, float* __restrict__ xc) {
  int c = blockIdx.x * 256 + threadIdx.x;  // 0..1791
  int m = blockIdx.y;
  int l = m & (SEQ - 1);
  const float* src = zxb + (size_t)m * LDZ + DINNER + c;
  float4 w = *(const float4*)(cw + (size_t)c * 4);
  float acc = cb[c];
#pragma unroll
  for (int k = 0; k < 4; ++k) {
    int ll = l + k - 3;
    if (ll >= 0) acc = fmaf(src[(ptrdiff_t)(k - 3) * LDZ], ((const float*)&w)[k], acc);
  }
  xc[(size_t)m * CONVDIM + c] = acc / (1.f + expf(-acc));
}

// ---------------- scan pass A: chunk-local final states (h starts at 0) ----------------
// block = (bh, chunk); lane = p (64), wave = n-quarter (4x32). B loads are wave-uniform -> s_load.
__global__ __launch_bounds__(256) void scanA(const float* __restrict__ xc, const float* __restrict__ dtS,
                                             const float* __restrict__ dAb, float* __restrict__ cstat,
                                             float* __restrict__ cdec) {
  const int bid = blockIdx.x;  // bh*16 + c
  const int c = bid & (NCHUNK - 1), bh = bid >> 4;
  const int b = bh / NHEADS, h = bh % NHEADS;
  const int lane = threadIdx.x & 63;
  const int w = __builtin_amdgcn_readfirstlane(threadIdx.x >> 6);
  const int m0 = b * SEQ + c * CHUNK;
  const float* xrow = xc + (size_t)m0 * CONVDIM + h * 64 + lane;
  const float* Brow = xc + (size_t)m0 * CONVDIM + DINNER + w * 32;
  const float* dAp = dAb + (size_t)m0 * NHEADS + h;
  const float* dtp = dtS + (size_t)m0 * NHEADS + h;
  float hreg[32];
#pragma unroll
  for (int j = 0; j < 32; ++j) hreg[j] = 0.f;
  float dprod = 1.f;
  for (int i = 0; i < CHUNK; ++i) {
    float xv = xrow[i * CONVDIM];
    float dA = dAp[i * NHEADS];
    float dt = dtp[i * NHEADS];
    float s = dt * xv;
    const float* Bp = Brow + (size_t)i * CONVDIM;
#pragma unroll
    for (int j = 0; j < 32; ++j) hreg[j] = fmaf(hreg[j], dA, s * Bp[j]);
    dprod *= dA;
  }
  float* dst = cstat + (size_t)bid * 8192 + lane * 128 + w * 32;
#pragma unroll
  for (int j = 0; j < 32; ++j) dst[j] = hreg[j];
  if (threadIdx.x == 0) cdec[bid] = dprod;
}

// ---------------- scan pass B: inter-chunk recurrence; rewrite cstat with h_start ----------------
__global__ __launch_bounds__(256) void scanB(float* __restrict__ cstat, const float* __restrict__ cdec) {
  const int bh = blockIdx.x;
  const int tid = threadIdx.x;
  float hreg[32];
#pragma unroll
  for (int j = 0; j < 32; ++j) hreg[j] = 0.f;
  for (int c = 0; c < NCHUNK; ++c) {
    float* p = cstat + (size_t)(bh * NCHUNK + c) * 8192 + tid * 32;
    const float P = cdec[bh * NCHUNK + c];
    float tmp[32];
#pragma unroll
    for (int j = 0; j < 32; ++j) tmp[j] = p[j];
#pragma unroll
    for (int j = 0; j < 32; ++j) p[j] = hreg[j];  // h_start for this chunk
#pragma unroll
    for (int j = 0; j < 32; ++j) hreg[j] = fmaf(hreg[j], P, tmp[j]);
  }
}

// ---------------- scan pass C: replay chunk from h_start, emit y (+D*x) ----------------
__global__ __launch_bounds__(256) void scanC(const float* __restrict__ xc, const float* __restrict__ dtS,
                                             const float* __restrict__ dAb, const float* __restrict__ cstat,
                                             const float* __restrict__ Dvec, float* __restrict__ zxb) {
  __shared__ float part[2][4][64];
  const int bid = blockIdx.x;
  const int c = bid & (NCHUNK - 1), bh = bid >> 4;
  const int b = bh / NHEADS, h = bh % NHEADS;
  const int lane = threadIdx.x & 63;
  const int w = __builtin_amdgcn_readfirstlane(threadIdx.x >> 6);
  const int m0 = b * SEQ + c * CHUNK;
  const float* xrow = xc + (size_t)m0 * CONVDIM + h * 64 + lane;
  const float* Brow = xc + (size_t)m0 * CONVDIM + DINNER + w * 32;
  const float* Crow = Brow + DSTATE;
  const float* dAp = dAb + (size_t)m0 * NHEADS + h;
  const float* dtp = dtS + (size_t)m0 * NHEADS + h;
  const float Dh = Dvec[h];
  float* yrow = zxb + (size_t)m0 * LDZ + DINNER + h * 64 + lane;  // y lives in dead xBC columns
  float hreg[32];
  {
    const float* src = cstat + (size_t)bid * 8192 + lane * 128 + w * 32;
#pragma unroll
    for (int j = 0; j < 32; ++j) hreg[j] = src[j];
  }
  for (int i = 0; i < CHUNK; ++i) {
    float xv = xrow[i * CONVDIM];
    float dA = dAp[i * NHEADS];
    float dt = dtp[i * NHEADS];
    float s = dt * xv;
    const float* Bp = Brow + (size_t)i * CONVDIM;
    const float* Cp = Crow + (size_t)i * CONVDIM;
    float acc = 0.f;
#pragma unroll
    for (int j = 0; j < 32; ++j) {
      hreg[j] = fmaf(hreg[j], dA, s * Bp[j]);
      acc = fmaf(hreg[j], Cp[j], acc);
    }
    part[i & 1][w][lane] = acc;
    __syncthreads();
    if (threadIdx.x < 64) {  // wave 0: combine 4 partials, add D*x, coalesced 256B store
      float y = part[i & 1][0][lane] + part[i & 1][1][lane] + part[i & 1][2][lane] + part[i & 1][3][lane] + Dh * xv;
      yrow[(size_t)i * LDZ] = y;
    }
  }
}

// ---------------- RMSNorm + silu(z) gate -> bf16 ----------------
__global__ __launch_bounds__(256) void norm_gate(const float* __restrict__ zxb, const float* __restrict__ nw,
                                                 __hip_bfloat16* __restrict__ yg) {
  const int m = blockIdx.x, tid = threadIdx.x;
  const float* zr = zxb + (size_t)m * LDZ;
  const float* yr = zr + DINNER;
  float yv[6], zv[6];
  float ss = 0.f;
#pragma unroll
  for (int jj = 0; jj < 6; ++jj) {
    int i = tid + jj * 256;
    yv[jj] = yr[i];
    zv[jj] = zr[i];
    ss = fmaf(yv[jj], yv[jj], ss);
  }
#pragma unroll
  for (int o = 32; o > 0; o >>= 1) ss += __shfl_down(ss, o);
  __shared__ float red[4];
  if ((tid & 63) == 0) red[tid >> 6] = ss;
  __syncthreads();
  float tot = red[0] + red[1] + red[2] + red[3];
  float r = rsqrtf(tot * (1.f / 1536.f) + 1e-5f);
#pragma unroll
  for (int jj = 0; jj < 6; ++jj) {
    int i = tid + jj * 256;
    float z = zv[jj];
    float g = z / (1.f + expf(-z));
    yg[(size_t)m * DINNER + i] = __float2bfloat16(nw[i] * yv[jj] * r * g);
  }
}

extern "C" void kernel_launch(void* const* d_in, const int* in_sizes, int n_in,
                              void* d_out, int out_size, void* d_ws, size_t ws_size,
                              hipStream_t stream) {
  (void)in_sizes; (void)n_in; (void)out_size; (void)ws_size;
  const float* u       = (const float*)d_in[0];
  const float* W_in    = (const float*)d_in[1];
  const float* conv_w  = (const float*)d_in[2];
  const float* conv_b  = (const float*)d_in[3];
  const float* dt_bias = (const float*)d_in[4];
  const float* A_log   = (const float*)d_in[5];
  const float* Dvec    = (const float*)d_in[6];
  const float* norm_w  = (const float*)d_in[7];
  const float* W_out   = (const float*)d_in[8];
  float* out = (float*)d_out;

  // workspace layout (~240 MB)
  float* zxb   = (float*)d_ws;                       // [8192][3328] f32
  float* xconv = zxb + (size_t)MTOT * LDZ;           // [8192][1792] f32
  float* cstat = xconv + (size_t)MTOT * CONVDIM;     // [1536][8192] f32
  float* dtS   = cstat + (size_t)NBH * NCHUNK * 8192;
  float* dAb   = dtS + (size_t)MTOT * NHEADS;
  float* cdec  = dAb + (size_t)MTOT * NHEADS;
  __hip_bfloat16* ub  = (__hip_bfloat16*)(cdec + NBH * NCHUNK);
  __hip_bfloat16* wib = ub + (size_t)NU;
  __hip_bfloat16* wob = wib + (size_t)NWI;
  __hip_bfloat16* yg  = (__hip_bfloat16*)xconv;      // alias: xconv dead after scanC

  cvt_bf16<<<(NU + NWI + NWO + 255) / 256, 256, 0, stream>>>(u, W_in, W_out, ub, wib, wob);
  gemm_bt<<<dim3(LDZ / 128, MTOT / 128), 256, 0, stream>>>(ub, wib, zxb, DMODEL, DMODEL, LDZ, DMODEL / 32);
  dt_kernel<<<MTOT, 256, 0, stream>>>(u, W_in, dt_bias, A_log, dtS, dAb);
  conv_silu<<<dim3(CONVDIM / 256, MTOT), 256, 0, stream>>>(zxb, conv_w, conv_b, xconv);
  scanA<<<NBH * NCHUNK, 256, 0, stream>>>(xconv, dtS, dAb, cstat, cdec);
  scanB<<<NBH, 256, 0, stream>>>(cstat, cdec);
  scanC<<<NBH * NCHUNK, 256, 0, stream>>>(xconv, dtS, dAb, cstat, Dvec, zxb);
  norm_gate<<<MTOT, 256, 0, stream>>>(zxb, norm_w, yg);
  gemm_bt<<<dim3(DMODEL / 128, MTOT / 128), 256, 0, stream>>>(yg, wob, out, DINNER, DINNER, DMODEL, DINNER / 32);
}

// Round 2
// 490.958 us; speedup vs baseline: 1.2731x; 1.2731x over previous
//
#include <hip/hip_runtime.h>
#include <hip/hip_bf16.h>

typedef __bf16 bf16x8 __attribute__((ext_vector_type(8)));
typedef float f32x4 __attribute__((ext_vector_type(4)));
typedef unsigned int u32x4 __attribute__((ext_vector_type(4)));

#define MTOT    8192
#define DMODEL  768
#define DINNER  1536
#define DSTATE  128
#define NHEADS  24
#define CONVDIM 1792
#define LDZ     3328
#define SEQ     2048
#define CHUNK   128
#define NCHUNK  16
#define NBH     96

#define NU   (MTOT*DMODEL)
#define NWI  (LDZ*DMODEL)
#define NWO  (DMODEL*DINNER)

// ---------------- f32 -> bf16 conversions ----------------
__global__ __launch_bounds__(256) void cvt_bf16(const float* __restrict__ u, const float* __restrict__ Wi,
                                                const float* __restrict__ Wo,
                                                __hip_bfloat16* __restrict__ ub, __hip_bfloat16* __restrict__ wib,
                                                __hip_bfloat16* __restrict__ wob) {
  int i = blockIdx.x * 256 + threadIdx.x;
  if (i < NU) ub[i] = __float2bfloat16(u[i]);
  else if (i < NU + NWI) { int k = i - NU; wib[k] = __float2bfloat16(Wi[k]); }
  else if (i < NU + NWI + NWO) { int k = i - NU - NWI; wob[k] = __float2bfloat16(Wo[k]); }
}

// ---------------- bf16 NT GEMM (unchanged from r1) ----------------
__global__ __launch_bounds__(256, 2) void gemm_bt(const __hip_bfloat16* __restrict__ A,
                                                  const __hip_bfloat16* __restrict__ B,
                                                  float* __restrict__ C, int lda, int ldb, int ldc, int nk) {
  __shared__ __align__(16) __hip_bfloat16 As[128 * 40];
  __shared__ __align__(16) __hip_bfloat16 Bs[128 * 40];
  const int tid = threadIdx.x;
  const int lane = tid & 63, wid = tid >> 6;
  const int wm = wid >> 1, wn = wid & 1;
  const int bm = blockIdx.y, bn = blockIdx.x;
  const int ra = tid >> 2, ka = tid & 3;
  const __hip_bfloat16* Ag0 = A + (size_t)(bm * 128 + ra) * lda + ka * 8;
  const __hip_bfloat16* Ag1 = Ag0 + (size_t)64 * lda;
  const __hip_bfloat16* Bg0 = B + (size_t)(bn * 128 + ra) * ldb + ka * 8;
  const __hip_bfloat16* Bg1 = Bg0 + (size_t)64 * ldb;
  f32x4 acc[4][4] = {};
  u32x4 a0 = *(const u32x4*)Ag0, a1 = *(const u32x4*)Ag1;
  u32x4 b0 = *(const u32x4*)Bg0, b1 = *(const u32x4*)Bg1;
  const int lr = lane & 15, lk = lane >> 4;
  const int arow = wm * 64 + lr, brow = wn * 64 + lr;
  for (int ks = 0; ks < nk; ++ks) {
    __syncthreads();
    *(u32x4*)&As[ra * 40 + ka * 8] = a0;
    *(u32x4*)&As[(ra + 64) * 40 + ka * 8] = a1;
    *(u32x4*)&Bs[ra * 40 + ka * 8] = b0;
    *(u32x4*)&Bs[(ra + 64) * 40 + ka * 8] = b1;
    __syncthreads();
    if (ks + 1 < nk) {
      a0 = *(const u32x4*)(Ag0 + (ks + 1) * 32);
      a1 = *(const u32x4*)(Ag1 + (ks + 1) * 32);
      b0 = *(const u32x4*)(Bg0 + (ks + 1) * 32);
      b1 = *(const u32x4*)(Bg1 + (ks + 1) * 32);
    }
    bf16x8 af[4], bfr[4];
#pragma unroll
    for (int i = 0; i < 4; ++i) {
      af[i] = *(const bf16x8*)&As[(arow + i * 16) * 40 + lk * 8];
      bfr[i] = *(const bf16x8*)&Bs[(brow + i * 16) * 40 + lk * 8];
    }
#pragma unroll
    for (int i = 0; i < 4; ++i)
#pragma unroll
      for (int j = 0; j < 4; ++j)
        acc[i][j] = __builtin_amdgcn_mfma_f32_16x16x32_bf16(af[i], bfr[j], acc[i][j], 0, 0, 0);
  }
  const int crow0 = bm * 128 + wm * 64 + lk * 4;
  const int ccol0 = bn * 128 + wn * 64 + lr;
#pragma unroll
  for (int i = 0; i < 4; ++i)
#pragma unroll
    for (int j = 0; j < 4; ++j)
#pragma unroll
      for (int r = 0; r < 4; ++r)
        C[(size_t)(crow0 + i * 16 + r) * ldc + ccol0 + j * 16] = acc[i][j][r];
}

// ---------------- fp32 dt path: softplus(dt)+dt*A ----------------
__global__ __launch_bounds__(256) void dt_kernel(const float* __restrict__ u, const float* __restrict__ Wi,
                                                 const float* __restrict__ dtb, const float* __restrict__ alog,
                                                 float* __restrict__ dtS, float* __restrict__ dtA) {
  int m = blockIdx.x;
  __shared__ __align__(16) float ush[DMODEL];
  for (int i = threadIdx.x; i < DMODEL; i += 256) ush[i] = u[(size_t)m * DMODEL + i];
  __syncthreads();
  int tid = threadIdx.x;
  if (tid < 192) {
    int h = tid >> 3, j = tid & 7;
    const float4* w4 = (const float4*)(Wi + (size_t)(LDZ + h) * DMODEL + j * 96);
    const float4* u4 = (const float4*)(ush + j * 96);
    float s = 0.f;
#pragma unroll
    for (int k = 0; k < 24; ++k) {
      float4 a = u4[k], b = w4[k];
      s += a.x * b.x + a.y * b.y + a.z * b.z + a.w * b.w;
    }
    s += __shfl_xor(s, 1);
    s += __shfl_xor(s, 2);
    s += __shfl_xor(s, 4);
    if (j == 0) {
      float x = s + dtb[h];
      float dt = (x > 20.f) ? x : log1pf(expf(x));
      dtS[(size_t)m * NHEADS + h] = dt;
      dtA[(size_t)m * NHEADS + h] = -expf(alog[h]) * dt;
    }
  }
}

// ---------------- per-(b,chunk) cumsum of dt*A over time ----------------
__global__ __launch_bounds__(256) void cumsum_kernel(const float* __restrict__ dtA, float* __restrict__ scum,
                                                     float* __restrict__ cdec) {
  int bc = blockIdx.x;  // b*16+c
  int b = bc >> 4, c = bc & 15;
  __shared__ float buf[CHUNK * NHEADS];
  int m0 = b * SEQ + c * CHUNK;
  for (int t = threadIdx.x; t < CHUNK * NHEADS; t += 256)
    buf[t] = dtA[(size_t)m0 * NHEADS + t];
  __syncthreads();
  if (threadIdx.x < NHEADS) {
    int h = threadIdx.x;
    float run = 0.f;
    float* dst = scum + ((size_t)bc * NHEADS + h) * CHUNK;
    for (int j = 0; j < CHUNK; ++j) { run += buf[j * NHEADS + h]; dst[j] = run; }
    cdec[(b * NHEADS + h) * NCHUNK + c] = __expf(run);
  }
}

// ---------------- conv + silu + pack bf16 operands (Xd = dt*x, B, C) ----------------
__global__ __launch_bounds__(256) void conv_prep(const float* __restrict__ zxb, const float* __restrict__ cw,
                                                 const float* __restrict__ cb, const float* __restrict__ dtS,
                                                 __hip_bfloat16* __restrict__ Xd, __hip_bfloat16* __restrict__ Bb,
                                                 __hip_bfloat16* __restrict__ Cb) {
  int c = blockIdx.x * 256 + threadIdx.x;
  int m = blockIdx.y;
  int l = m & (SEQ - 1);
  const float* src = zxb + (size_t)m * LDZ + DINNER + c;
  float4 w = *(const float4*)(cw + (size_t)c * 4);
  float acc = cb[c];
#pragma unroll
  for (int k = 0; k < 4; ++k) {
    int ll = l + k - 3;
    if (ll >= 0) acc = fmaf(src[(ptrdiff_t)(k - 3) * LDZ], ((const float*)&w)[k], acc);
  }
  float v = acc / (1.f + __expf(-acc));
  if (c < DINNER) Xd[(size_t)m * DINNER + c] = __float2bfloat16(dtS[m * NHEADS + (c >> 6)] * v);
  else if (c < DINNER + DSTATE) Bb[(size_t)m * DSTATE + (c - DINNER)] = __float2bfloat16(v);
  else Cb[(size_t)m * DSTATE + (c - DINNER - DSTATE)] = __float2bfloat16(v);
}

// ---------------- 64x64 bf16 transposes: Xd->XdT (time-contig), Bb->Bt ----------------
__global__ __launch_bounds__(256) void transp(const __hip_bfloat16* __restrict__ Xd,
                                              const __hip_bfloat16* __restrict__ Bb,
                                              __hip_bfloat16* __restrict__ XdT, __hip_bfloat16* __restrict__ Bt) {
  __shared__ __hip_bfloat16 t[64][72];
  int bid = blockIdx.x;
  const __hip_bfloat16* src;
  __hip_bfloat16* dst;
  int srcld;
  if (bid < 3072) {  // Xd tiles
    int tm = bid & 127, tc = bid >> 7;
    int m0 = tm * 64, c0 = tc * 64, b = m0 >> 11;
    src = Xd + (size_t)m0 * DINNER + c0; srcld = DINNER;
    dst = XdT + ((size_t)(b * DINNER + c0)) * SEQ + (m0 - b * SEQ);
  } else {  // B tiles
    int k = bid - 3072;
    int tm = k & 127, tn = k >> 7;
    int m0 = tm * 64, n0 = tn * 64, b = m0 >> 11;
    src = Bb + (size_t)m0 * DSTATE + n0; srcld = DSTATE;
    dst = Bt + ((size_t)(b * DSTATE + n0)) * SEQ + (m0 - b * SEQ);
  }
  int r = threadIdx.x >> 2, cc = (threadIdx.x & 3) * 16;
  *(u32x4*)&t[r][cc] = *(const u32x4*)(src + (size_t)r * srcld + cc);
  *(u32x4*)&t[r][cc + 8] = *(const u32x4*)(src + (size_t)r * srcld + cc + 8);
  __syncthreads();
  __hip_bfloat16 tmp[16] __attribute__((aligned(16)));
#pragma unroll
  for (int k2 = 0; k2 < 16; ++k2) tmp[k2] = t[cc + k2][r];
  *(u32x4*)(dst + (size_t)r * SEQ + cc) = *(u32x4*)&tmp[0];
  *(u32x4*)(dst + (size_t)r * SEQ + cc + 8) = *(u32x4*)&tmp[8];
}

// ---------------- chunk-local end state: T[p][n] = sum_j exp(S-s_j)*Xd[j][p]*B[j][n] ----------------
__global__ __launch_bounds__(256, 2) void state_gemm(const __hip_bfloat16* __restrict__ XdT,
                                                     const __hip_bfloat16* __restrict__ Bt,
                                                     const float* __restrict__ scum, float* __restrict__ cstat) {
  __shared__ __align__(16) __hip_bfloat16 Xw[64 * 136];
  __shared__ __align__(16) __hip_bfloat16 Bts[128 * 136];
  __shared__ float rS[CHUNK];
  int bid = blockIdx.x;
  int c = bid & 15, bh = bid >> 4;
  int b = bh / NHEADS, h = bh % NHEADS;
  const float* sp = scum + ((size_t)(b * NCHUNK + c) * NHEADS + h) * CHUNK;
  int tid = threadIdx.x;
  if (tid < CHUNK) rS[tid] = __expf(sp[CHUNK - 1] - sp[tid]);
  {
    int n = tid >> 1, jc = (tid & 1) * 64;
    const __hip_bfloat16* g = Bt + ((size_t)(b * DSTATE + n)) * SEQ + c * CHUNK + jc;
#pragma unroll
    for (int q = 0; q < 8; ++q) *(u32x4*)&Bts[n * 136 + jc + q * 8] = *(const u32x4*)(g + q * 8);
  }
  __syncthreads();
  {
    int p = tid >> 2, jc = (tid & 3) * 32;
    const __hip_bfloat16* g = XdT + ((size_t)((b * NHEADS + h) * 64 + p)) * SEQ + c * CHUNK + jc;
#pragma unroll
    for (int q = 0; q < 4; ++q) {
      bf16x8 vv = *(const bf16x8*)(g + q * 8);
      bf16x8 ov;
#pragma unroll
      for (int e = 0; e < 8; ++e) ov[e] = (__bf16)((float)vv[e] * rS[jc + q * 8 + e]);
      *(bf16x8*)&Xw[p * 136 + jc + q * 8] = ov;
    }
  }
  __syncthreads();
  const int lane = tid & 63, wid = tid >> 6;
  const int wm = wid >> 1, wn = wid & 1;
  const int lr = lane & 15, lk = lane >> 4;
  f32x4 acc[2][4] = {};
#pragma unroll
  for (int ks = 0; ks < 4; ++ks) {
    bf16x8 af[2], bq[4];
#pragma unroll
    for (int i = 0; i < 2; ++i) af[i] = *(const bf16x8*)&Xw[(wm * 32 + i * 16 + lr) * 136 + ks * 32 + lk * 8];
#pragma unroll
    for (int j = 0; j < 4; ++j) bq[j] = *(const bf16x8*)&Bts[(wn * 64 + j * 16 + lr) * 136 + ks * 32 + lk * 8];
#pragma unroll
    for (int i = 0; i < 2; ++i)
#pragma unroll
      for (int j = 0; j < 4; ++j)
        acc[i][j] = __builtin_amdgcn_mfma_f32_16x16x32_bf16(af[i], bq[j], acc[i][j], 0, 0, 0);
  }
  float* dst = cstat + (size_t)bid * 8192;
#pragma unroll
  for (int i = 0; i < 2; ++i)
#pragma unroll
    for (int j = 0; j < 4; ++j)
#pragma unroll
      for (int r = 0; r < 4; ++r)
        dst[(wm * 32 + i * 16 + lk * 4 + r) * 128 + wn * 64 + j * 16 + lr] = acc[i][j][r];
}

// ---------------- inter-chunk recurrence (rewrites cstat with h_start) ----------------
__global__ __launch_bounds__(256) void scanB(float* __restrict__ cstat, const float* __restrict__ cdec) {
  const int bh = blockIdx.x;
  const int tid = threadIdx.x;
  float hreg[32];
#pragma unroll
  for (int j = 0; j < 32; ++j) hreg[j] = 0.f;
  for (int c = 0; c < NCHUNK; ++c) {
    float* p = cstat + (size_t)(bh * NCHUNK + c) * 8192 + tid * 32;
    const float P = cdec[bh * NCHUNK + c];
    float tmp[32];
#pragma unroll
    for (int j = 0; j < 32; ++j) tmp[j] = p[j];
#pragma unroll
    for (int j = 0; j < 32; ++j) p[j] = hreg[j];
#pragma unroll
    for (int j = 0; j < 32; ++j) hreg[j] = fmaf(hreg[j], P, tmp[j]);
  }
}

// ---------------- SSD y kernel: Y = (mask∘(C·Bᵀ))·Xd + exp(s_i)·C·h_startᵀ + D*x ----------------
template <int JE>
__global__ __launch_bounds__(256, 2) void ssd_y(const __hip_bfloat16* __restrict__ Cb,
                                                const __hip_bfloat16* __restrict__ Bb,
                                                const __hip_bfloat16* __restrict__ XdT,
                                                const __hip_bfloat16* __restrict__ Xd,
                                                const float* __restrict__ cstat, const float* __restrict__ scum,
                                                const float* __restrict__ dtS, const float* __restrict__ Dvec,
                                                float* __restrict__ zxb) {
  constexpr int HI = JE - 64;   // i-offset of this half-chunk
  constexpr int JW = JE / 2;    // per-wave j width
  constexpr int FJ = JW / 16;   // j frags per wave
  constexpr int KJ = JE / 32;   // k-steps over j
  __shared__ __align__(16) __hip_bfloat16 Cs[64 * 136];   // C tile, then M (masked scores)
  __shared__ __align__(16) __hip_bfloat16 Bs[JE * 136];   // B tile
  __shared__ __align__(16) __hip_bfloat16 R3[64 * 136];   // h_startT tile, then XdT tile
  __shared__ float sS[CHUNK];
  int bid = blockIdx.x;
  int c = bid & 15, bh = bid >> 4;
  int b = bh / NHEADS, h = bh % NHEADS;
  int m0 = b * SEQ + c * CHUNK;
  int tid = threadIdx.x;
  const float* sp = scum + ((size_t)(b * NCHUNK + c) * NHEADS + h) * CHUNK;
  if (tid < CHUNK) sS[tid] = sp[tid];
  {  // stage C [64 i][128 n]
    int r = tid >> 2, nc = (tid & 3) * 32;
    const __hip_bfloat16* g = Cb + (size_t)(m0 + HI + r) * DSTATE + nc;
#pragma unroll
    for (int q = 0; q < 4; ++q) *(u32x4*)&Cs[r * 136 + nc + q * 8] = *(const u32x4*)(g + q * 8);
  }
  if (JE == 64) {  // stage B [64 j][128 n]
    int r = tid >> 2, nc = (tid & 3) * 32;
    const __hip_bfloat16* g = Bb + (size_t)(m0 + r) * DSTATE + nc;
#pragma unroll
    for (int q = 0; q < 4; ++q) *(u32x4*)&Bs[r * 136 + nc + q * 8] = *(const u32x4*)(g + q * 8);
  } else {  // [128 j][128 n]
    int r = tid >> 1, nc = (tid & 1) * 64;
    const __hip_bfloat16* g = Bb + (size_t)(m0 + r) * DSTATE + nc;
#pragma unroll
    for (int q = 0; q < 8; ++q) *(u32x4*)&Bs[r * 136 + nc + q * 8] = *(const u32x4*)(g + q * 8);
  }
  {  // stage h_startT [64 p][128 n] f32->bf16
    int p = tid >> 2, nc = (tid & 3) * 32;
    const float* g = cstat + (size_t)bid * 8192 + p * 128 + nc;
#pragma unroll
    for (int q = 0; q < 4; ++q) {
      f32x4 v0 = *(const f32x4*)(g + q * 8);
      f32x4 v1 = *(const f32x4*)(g + q * 8 + 4);
      bf16x8 ov;
      ov[0] = (__bf16)v0[0]; ov[1] = (__bf16)v0[1]; ov[2] = (__bf16)v0[2]; ov[3] = (__bf16)v0[3];
      ov[4] = (__bf16)v1[0]; ov[5] = (__bf16)v1[1]; ov[6] = (__bf16)v1[2]; ov[7] = (__bf16)v1[3];
      *(bf16x8*)&R3[p * 136 + nc + q * 8] = ov;
    }
  }
  __syncthreads();
  const int lane = tid & 63, wid = tid >> 6;
  const int wm = wid >> 1, wn = wid & 1;
  const int lr = lane & 15, lk = lane >> 4;
  f32x4 Gacc[2][FJ] = {};
  f32x4 Uacc[2][2] = {};
  // U = C·h_startT  (contract n)
#pragma unroll
  for (int ks = 0; ks < 4; ++ks) {
    bf16x8 af[2], bq[2];
#pragma unroll
    for (int i = 0; i < 2; ++i) af[i] = *(const bf16x8*)&Cs[(wm * 32 + i * 16 + lr) * 136 + ks * 32 + lk * 8];
#pragma unroll
    for (int j = 0; j < 2; ++j) bq[j] = *(const bf16x8*)&R3[(wn * 32 + j * 16 + lr) * 136 + ks * 32 + lk * 8];
#pragma unroll
    for (int i = 0; i < 2; ++i)
#pragma unroll
      for (int j = 0; j < 2; ++j)
        Uacc[i][j] = __builtin_amdgcn_mfma_f32_16x16x32_bf16(af[i], bq[j], Uacc[i][j], 0, 0, 0);
  }
  // G = C·Bᵀ (contract n)
#pragma unroll
  for (int ks = 0; ks < 4; ++ks) {
    bf16x8 af[2], bq[FJ];
#pragma unroll
    for (int i = 0; i < 2; ++i) af[i] = *(const bf16x8*)&Cs[(wm * 32 + i * 16 + lr) * 136 + ks * 32 + lk * 8];
#pragma unroll
    for (int j = 0; j < FJ; ++j) bq[j] = *(const bf16x8*)&Bs[(wn * JW + j * 16 + lr) * 136 + ks * 32 + lk * 8];
#pragma unroll
    for (int i = 0; i < 2; ++i)
#pragma unroll
      for (int j = 0; j < FJ; ++j)
        Gacc[i][j] = __builtin_amdgcn_mfma_f32_16x16x32_bf16(af[i], bq[j], Gacc[i][j], 0, 0, 0);
  }
  __syncthreads();  // all reads of Cs/Bs/R3 done
  {                 // mask+scale G -> M (into Cs region)
    float siv[2][4];
#pragma unroll
    for (int i = 0; i < 2; ++i)
#pragma unroll
      for (int r = 0; r < 4; ++r) siv[i][r] = sS[HI + wm * 32 + i * 16 + lk * 4 + r];
#pragma unroll
    for (int i = 0; i < 2; ++i)
#pragma unroll
      for (int j = 0; j < FJ; ++j) {
        int gj = wn * JW + j * 16 + lr;
        float sj = sS[gj];
#pragma unroll
        for (int r = 0; r < 4; ++r) {
          int il = wm * 32 + i * 16 + lk * 4 + r;
          int gi = HI + il;
          float mv = (gj <= gi) ? Gacc[i][j][r] * __expf(siv[i][r] - sj) : 0.f;
          Cs[il * 136 + gj] = __float2bfloat16(mv);
        }
      }
  }
  {  // stage XdT tile [64 p][JE j] into R3
    int p = tid >> 2, jc = (tid & 3) * (JE / 4);
    const __hip_bfloat16* g = XdT + ((size_t)((b * NHEADS + h) * 64 + p)) * SEQ + c * CHUNK + jc;
#pragma unroll
    for (int q = 0; q < JE / 32; ++q) *(u32x4*)&R3[p * 136 + jc + q * 8] = *(const u32x4*)(g + q * 8);
  }
  __syncthreads();
  // Y_intra = M·Xd (contract j)
  f32x4 Yacc[2][2] = {};
#pragma unroll
  for (int ks = 0; ks < KJ; ++ks) {
    bf16x8 af[2], bq[2];
#pragma unroll
    for (int i = 0; i < 2; ++i) af[i] = *(const bf16x8*)&Cs[(wm * 32 + i * 16 + lr) * 136 + ks * 32 + lk * 8];
#pragma unroll
    for (int j = 0; j < 2; ++j) bq[j] = *(const bf16x8*)&R3[(wn * 32 + j * 16 + lr) * 136 + ks * 32 + lk * 8];
#pragma unroll
    for (int i = 0; i < 2; ++i)
#pragma unroll
      for (int j = 0; j < 2; ++j)
        Yacc[i][j] = __builtin_amdgcn_mfma_f32_16x16x32_bf16(af[i], bq[j], Yacc[i][j], 0, 0, 0);
  }
  // epilogue: y = Y_intra + exp(s_i)*U + D*x
  const float Dh = Dvec[h];
#pragma unroll
  for (int i = 0; i < 2; ++i)
#pragma unroll
    for (int r = 0; r < 4; ++r) {
      int il = wm * 32 + i * 16 + lk * 4 + r;
      int gi = HI + il;
      int m = m0 + gi;
      float ei = __expf(sS[gi]);
      float dt = dtS[(size_t)m * NHEADS + h];
#pragma unroll
      for (int j = 0; j < 2; ++j) {
        int p = wn * 32 + j * 16 + lr;
        float xv = (float)Xd[(size_t)m * DINNER + h * 64 + p] / dt;
        zxb[(size_t)m * LDZ + DINNER + h * 64 + p] = Yacc[i][j][r] + ei * Uacc[i][j][r] + Dh * xv;
      }
    }
}

// ---------------- RMSNorm + silu(z) gate -> bf16 ----------------
__global__ __launch_bounds__(256) void norm_gate(const float* __restrict__ zxb, const float* __restrict__ nw,
                                                 __hip_bfloat16* __restrict__ yg) {
  const int m = blockIdx.x, tid = threadIdx.x;
  const float* zr = zxb + (size_t)m * LDZ;
  const float* yr = zr + DINNER;
  float yv[6], zv[6];
  float ss = 0.f;
#pragma unroll
  for (int jj = 0; jj < 6; ++jj) {
    int i = tid + jj * 256;
    yv[jj] = yr[i];
    zv[jj] = zr[i];
    ss = fmaf(yv[jj], yv[jj], ss);
  }
#pragma unroll
  for (int o = 32; o > 0; o >>= 1) ss += __shfl_down(ss, o);
  __shared__ float red[4];
  if ((tid & 63) == 0) red[tid >> 6] = ss;
  __syncthreads();
  float tot = red[0] + red[1] + red[2] + red[3];
  float r = rsqrtf(tot * (1.f / 1536.f) + 1e-5f);
#pragma unroll
  for (int jj = 0; jj < 6; ++jj) {
    int i = tid + jj * 256;
    float z = zv[jj];
    float g = z / (1.f + __expf(-z));
    yg[(size_t)m * DINNER + i] = __float2bfloat16(nw[i] * yv[jj] * r * g);
  }
}

extern "C" void kernel_launch(void* const* d_in, const int* in_sizes, int n_in,
                              void* d_out, int out_size, void* d_ws, size_t ws_size,
                              hipStream_t stream) {
  (void)in_sizes; (void)n_in; (void)out_size; (void)ws_size;
  const float* u       = (const float*)d_in[0];
  const float* W_in    = (const float*)d_in[1];
  const float* conv_w  = (const float*)d_in[2];
  const float* conv_b  = (const float*)d_in[3];
  const float* dt_bias = (const float*)d_in[4];
  const float* A_log   = (const float*)d_in[5];
  const float* Dvec    = (const float*)d_in[6];
  const float* norm_w  = (const float*)d_in[7];
  const float* W_out   = (const float*)d_in[8];
  float* out = (float*)d_out;

  float* zxb   = (float*)d_ws;                    // 8192*3328
  float* cstat = zxb + (size_t)MTOT * LDZ;        // 1536*8192
  float* dtS   = cstat + (size_t)NBH * NCHUNK * 8192;
  float* dtA   = dtS + (size_t)MTOT * NHEADS;
  float* scum  = dtA + (size_t)MTOT * NHEADS;
  float* cdec  = scum + (size_t)MTOT * NHEADS;
  __hip_bfloat16* ub  = (__hip_bfloat16*)(cdec + NBH * NCHUNK);
  __hip_bfloat16* wib = ub + (size_t)NU;
  __hip_bfloat16* wob = wib + (size_t)NWI;
  __hip_bfloat16* Xd  = wob + (size_t)NWO;
  __hip_bfloat16* Bb  = Xd + (size_t)MTOT * DINNER;
  __hip_bfloat16* Cb  = Bb + (size_t)MTOT * DSTATE;
  __hip_bfloat16* XdT = Cb + (size_t)MTOT * DSTATE;
  __hip_bfloat16* Bt  = XdT + (size_t)MTOT * DINNER;
  __hip_bfloat16* yg  = Xd;  // alias: Xd dead after ssd_y

  cvt_bf16<<<(NU + NWI + NWO + 255) / 256, 256, 0, stream>>>(u, W_in, W_out, ub, wib, wob);
  gemm_bt<<<dim3(LDZ / 128, MTOT / 128), 256, 0, stream>>>(ub, wib, zxb, DMODEL, DMODEL, LDZ, DMODEL / 32);
  dt_kernel<<<MTOT, 256, 0, stream>>>(u, W_in, dt_bias, A_log, dtS, dtA);
  cumsum_kernel<<<64, 256, 0, stream>>>(dtA, scum, cdec);
  conv_prep<<<dim3(CONVDIM / 256, MTOT), 256, 0, stream>>>(zxb, conv_w, conv_b, dtS, Xd, Bb, Cb);
  transp<<<3072 + 256, 256, 0, stream>>>(Xd, Bb, XdT, Bt);
  state_gemm<<<NBH * NCHUNK, 256, 0, stream>>>(XdT, Bt, scum, cstat);
  scanB<<<NBH, 256, 0, stream>>>(cstat, cdec);
  ssd_y<64><<<NBH * NCHUNK, 256, 0, stream>>>(Cb, Bb, XdT, Xd, cstat, scum, dtS, Dvec, zxb);
  ssd_y<128><<<NBH * NCHUNK, 256, 0, stream>>>(Cb, Bb, XdT, Xd, cstat, scum, dtS, Dvec, zxb);
  norm_gate<<<MTOT, 256, 0, stream>>>(zxb, norm_w, yg);
  gemm_bt<<<dim3(DMODEL / 128, MTOT / 128), 256, 0, stream>>>(yg, wob, out, DINNER, DINNER, DMODEL, DINNER / 32);
}

// Round 3
// 416.660 us; speedup vs baseline: 1.5001x; 1.1783x over previous
//
#include <hip/hip_runtime.h>
#include <hip/hip_bf16.h>

typedef __bf16 bf16x8 __attribute__((ext_vector_type(8)));
typedef float f32x4 __attribute__((ext_vector_type(4)));
typedef unsigned int u32x4 __attribute__((ext_vector_type(4)));

#define MTOT    8192
#define DMODEL  768
#define DINNER  1536
#define DSTATE  128
#define NHEADS  24
#define CONVDIM 1792
#define LDZ     3328
#define SEQ     2048
#define CHUNK   128
#define NCHUNK  16
#define NBH     96

#define NU   (MTOT*DMODEL)
#define NWI  (LDZ*DMODEL)
#define NWO  (DMODEL*DINNER)
#define NWD  (32*DMODEL)      // padded dt-weight rows (24 real + 8 zero)

// async global->LDS, 16B per lane; LDS dest = wave-uniform base + lane*16
__device__ __forceinline__ void gl2lds16(const __hip_bfloat16* g, __hip_bfloat16* l) {
  __builtin_amdgcn_global_load_lds((const __attribute__((address_space(1))) void*)g,
                                   (__attribute__((address_space(3))) void*)l, 16, 0, 0);
}

// ---------------- f32 -> bf16 conversions (+ padded hi/lo dt weights) ----------------
__global__ __launch_bounds__(256) void cvt_bf16(const float* __restrict__ u, const float* __restrict__ Wi,
                                                const float* __restrict__ Wo,
                                                __hip_bfloat16* __restrict__ ub, __hip_bfloat16* __restrict__ wib,
                                                __hip_bfloat16* __restrict__ wob,
                                                __hip_bfloat16* __restrict__ wdh, __hip_bfloat16* __restrict__ wdl) {
  int i = blockIdx.x * 256 + threadIdx.x;
  if (i < NU) ub[i] = __float2bfloat16(u[i]);
  else if (i < NU + NWI) { int k = i - NU; wib[k] = __float2bfloat16(Wi[k]); }
  else if (i < NU + NWI + NWO) { int k = i - NU - NWI; wob[k] = __float2bfloat16(Wo[k]); }
  else if (i < NU + NWI + NWO + 2 * NWD) {
    int k = i - NU - NWI - NWO;
    int lo = (k >= NWD);
    if (lo) k -= NWD;
    int row = k / DMODEL, col = k - row * DMODEL;
    float w = (row < NHEADS) ? Wi[(size_t)(LDZ + row) * DMODEL + col] : 0.f;
    __hip_bfloat16 h = __float2bfloat16(w);
    if (!lo) wdh[k] = h;
    else wdl[k] = __float2bfloat16(w - __bfloat162float(h));
  }
}

// ---------------- bf16 NT GEMM, m97 structure: global_load_lds + linear LDS ----------------
__global__ __launch_bounds__(256, 2) void gemm_bt(const __hip_bfloat16* __restrict__ A,
                                                  const __hip_bfloat16* __restrict__ B,
                                                  float* __restrict__ C, int lda, int ldb, int ldc, int nk) {
  __shared__ __align__(16) __hip_bfloat16 As[128 * 32];
  __shared__ __align__(16) __hip_bfloat16 Bs[128 * 32];
  const int tid = threadIdx.x;
  const int lane = tid & 63, wid = tid >> 6;
  const int wm = wid >> 1, wn = wid & 1;
  const int bm = blockIdx.y, bn = blockIdx.x;
  // staging: wave wid covers rows wid*32..+31 (two 16-row issues); lane l -> row +l/4, 16B chunk l%4
  const int sr = (lane >> 2), sc = (lane & 3) * 8;
  const __hip_bfloat16* Ag0 = A + (size_t)(bm * 128 + wid * 32 + sr) * lda + sc;
  const __hip_bfloat16* Ag1 = Ag0 + (size_t)16 * lda;
  const __hip_bfloat16* Bg0 = B + (size_t)(bn * 128 + wid * 32 + sr) * ldb + sc;
  const __hip_bfloat16* Bg1 = Bg0 + (size_t)16 * ldb;
  __hip_bfloat16* Al0 = &As[(wid * 32) * 32];
  __hip_bfloat16* Al1 = &As[(wid * 32 + 16) * 32];
  __hip_bfloat16* Bl0 = &Bs[(wid * 32) * 32];
  __hip_bfloat16* Bl1 = &Bs[(wid * 32 + 16) * 32];
  f32x4 acc[4][4] = {};
  const int lr = lane & 15, lk = lane >> 4;
  const int arow = wm * 64 + lr, brow = wn * 64 + lr;
  for (int ks = 0; ks < nk; ++ks) {
    gl2lds16(Ag0 + ks * 32, Al0);
    gl2lds16(Ag1 + ks * 32, Al1);
    gl2lds16(Bg0 + ks * 32, Bl0);
    gl2lds16(Bg1 + ks * 32, Bl1);
    __syncthreads();  // drains vmcnt -> tiles ready
    bf16x8 af[4], bfr[4];
#pragma unroll
    for (int i = 0; i < 4; ++i) {
      af[i] = *(const bf16x8*)&As[(arow + i * 16) * 32 + lk * 8];
      bfr[i] = *(const bf16x8*)&Bs[(brow + i * 16) * 32 + lk * 8];
    }
#pragma unroll
    for (int i = 0; i < 4; ++i)
#pragma unroll
      for (int j = 0; j < 4; ++j)
        acc[i][j] = __builtin_amdgcn_mfma_f32_16x16x32_bf16(af[i], bfr[j], acc[i][j], 0, 0, 0);
    __syncthreads();  // all LDS reads done before next stage overwrites
  }
  const int crow0 = bm * 128 + wm * 64 + lk * 4;
  const int ccol0 = bn * 128 + wn * 64 + lr;
#pragma unroll
  for (int i = 0; i < 4; ++i)
#pragma unroll
    for (int j = 0; j < 4; ++j)
#pragma unroll
      for (int r = 0; r < 4; ++r)
        C[(size_t)(crow0 + i * 16 + r) * ldc + ccol0 + j * 16] = acc[i][j][r];
}

// ---------------- dt path: split-bf16 MFMA GEMM (fp32-grade) + softplus epilogue ----------------
// dtraw = uh*Wh + uh*Wl + ul*Wh ; tile M=64, N=32(24 valid), K=768
__global__ __launch_bounds__(256) void dt_mfma(const float* __restrict__ u,
                                               const __hip_bfloat16* __restrict__ wdh,
                                               const __hip_bfloat16* __restrict__ wdl,
                                               const float* __restrict__ dtb, const float* __restrict__ alog,
                                               float* __restrict__ dtS, float* __restrict__ dtA) {
  __shared__ __align__(16) __hip_bfloat16 Uh[64 * 32];
  __shared__ __align__(16) __hip_bfloat16 Ul[64 * 32];
  const int tid = threadIdx.x;
  const int lane = tid & 63, wid = tid >> 6;
  const int lr = lane & 15, lk = lane >> 4;
  const int bm = blockIdx.x;
  const int r = tid >> 2, c0 = (tid & 3) * 8;
  const float* usrc = u + (size_t)(bm * 64 + r) * DMODEL + c0;
  f32x4 acc[2] = {};
  for (int ks = 0; ks < DMODEL / 32; ++ks) {
    float4 v0 = *(const float4*)(usrc + ks * 32);
    float4 v1 = *(const float4*)(usrc + ks * 32 + 4);
    bf16x8 hi, lo;
    const float* vf = (const float*)&v0;
#pragma unroll
    for (int e = 0; e < 4; ++e) {
      __hip_bfloat16 h = __float2bfloat16(vf[e]);
      hi[e] = *(__bf16*)&h;
      __hip_bfloat16 l2 = __float2bfloat16(vf[e] - __bfloat162float(h));
      lo[e] = *(__bf16*)&l2;
    }
    vf = (const float*)&v1;
#pragma unroll
    for (int e = 0; e < 4; ++e) {
      __hip_bfloat16 h = __float2bfloat16(vf[e]);
      hi[4 + e] = *(__bf16*)&h;
      __hip_bfloat16 l2 = __float2bfloat16(vf[e] - __bfloat162float(h));
      lo[4 + e] = *(__bf16*)&l2;
    }
    *(bf16x8*)&Uh[r * 32 + c0] = hi;
    *(bf16x8*)&Ul[r * 32 + c0] = lo;
    __syncthreads();
    bf16x8 ah = *(const bf16x8*)&Uh[(wid * 16 + lr) * 32 + lk * 8];
    bf16x8 al = *(const bf16x8*)&Ul[(wid * 16 + lr) * 32 + lk * 8];
#pragma unroll
    for (int j = 0; j < 2; ++j) {
      bf16x8 bh = *(const bf16x8*)(wdh + (size_t)(j * 16 + lr) * DMODEL + ks * 32 + lk * 8);
      bf16x8 bl = *(const bf16x8*)(wdl + (size_t)(j * 16 + lr) * DMODEL + ks * 32 + lk * 8);
      acc[j] = __builtin_amdgcn_mfma_f32_16x16x32_bf16(ah, bh, acc[j], 0, 0, 0);
      acc[j] = __builtin_amdgcn_mfma_f32_16x16x32_bf16(ah, bl, acc[j], 0, 0, 0);
      acc[j] = __builtin_amdgcn_mfma_f32_16x16x32_bf16(al, bh, acc[j], 0, 0, 0);
    }
    __syncthreads();
  }
#pragma unroll
  for (int j = 0; j < 2; ++j) {
    int col = j * 16 + lr;
    if (col < NHEADS) {
      float nA = -expf(alog[col]);
      float bia = dtb[col];
#pragma unroll
      for (int rr = 0; rr < 4; ++rr) {
        int row = bm * 64 + wid * 16 + lk * 4 + rr;
        float x = acc[j][rr] + bia;
        float dt = (x > 20.f) ? x : log1pf(expf(x));
        dtS[(size_t)row * NHEADS + col] = dt;
        dtA[(size_t)row * NHEADS + col] = nA * dt;
      }
    }
  }
}

// ---------------- per-(b,chunk) cumsum of dt*A over time ----------------
__global__ __launch_bounds__(256) void cumsum_kernel(const float* __restrict__ dtA, float* __restrict__ scum,
                                                     float* __restrict__ cdec) {
  int bc = blockIdx.x;  // b*16+c
  int b = bc >> 4, c = bc & 15;
  __shared__ float buf[CHUNK * NHEADS];
  int m0 = b * SEQ + c * CHUNK;
  for (int t = threadIdx.x; t < CHUNK * NHEADS; t += 256)
    buf[t] = dtA[(size_t)m0 * NHEADS + t];
  __syncthreads();
  if (threadIdx.x < NHEADS) {
    int h = threadIdx.x;
    float run = 0.f;
    float* dst = scum + ((size_t)bc * NHEADS + h) * CHUNK;
    for (int j = 0; j < CHUNK; ++j) { run += buf[j * NHEADS + h]; dst[j] = run; }
    cdec[(b * NHEADS + h) * NCHUNK + c] = __expf(run);
  }
}

// ---------------- conv + silu + pack bf16 operands (Xd = dt*x, B, C) ----------------
__global__ __launch_bounds__(256) void conv_prep(const float* __restrict__ zxb, const float* __restrict__ cw,
                                                 const float* __restrict__ cb, const float* __restrict__ dtS,
                                                 __hip_bfloat16* __restrict__ Xd, __hip_bfloat16* __restrict__ Bb,
                                                 __hip_bfloat16* __restrict__ Cb) {
  int c = blockIdx.x * 256 + threadIdx.x;
  int m = blockIdx.y;
  int l = m & (SEQ - 1);
  const float* src = zxb + (size_t)m * LDZ + DINNER + c;
  float4 w = *(const float4*)(cw + (size_t)c * 4);
  float acc = cb[c];
#pragma unroll
  for (int k = 0; k < 4; ++k) {
    int ll = l + k - 3;
    if (ll >= 0) acc = fmaf(src[(ptrdiff_t)(k - 3) * LDZ], ((const float*)&w)[k], acc);
  }
  float v = acc / (1.f + __expf(-acc));
  if (c < DINNER) Xd[(size_t)m * DINNER + c] = __float2bfloat16(dtS[m * NHEADS + (c >> 6)] * v);
  else if (c < DINNER + DSTATE) Bb[(size_t)m * DSTATE + (c - DINNER)] = __float2bfloat16(v);
  else Cb[(size_t)m * DSTATE + (c - DINNER - DSTATE)] = __float2bfloat16(v);
}

// ---------------- 64x64 bf16 transposes: Xd->XdT (time-contig), Bb->Bt ----------------
__global__ __launch_bounds__(256) void transp(const __hip_bfloat16* __restrict__ Xd,
                                              const __hip_bfloat16* __restrict__ Bb,
                                              __hip_bfloat16* __restrict__ XdT, __hip_bfloat16* __restrict__ Bt) {
  __shared__ __hip_bfloat16 t[64][72];
  int bid = blockIdx.x;
  const __hip_bfloat16* src;
  __hip_bfloat16* dst;
  int srcld;
  if (bid < 3072) {
    int tm = bid & 127, tc = bid >> 7;
    int m0 = tm * 64, c0 = tc * 64, b = m0 >> 11;
    src = Xd + (size_t)m0 * DINNER + c0; srcld = DINNER;
    dst = XdT + ((size_t)(b * DINNER + c0)) * SEQ + (m0 - b * SEQ);
  } else {
    int k = bid - 3072;
    int tm = k & 127, tn = k >> 7;
    int m0 = tm * 64, n0 = tn * 64, b = m0 >> 11;
    src = Bb + (size_t)m0 * DSTATE + n0; srcld = DSTATE;
    dst = Bt + ((size_t)(b * DSTATE + n0)) * SEQ + (m0 - b * SEQ);
  }
  int r = threadIdx.x >> 2, cc = (threadIdx.x & 3) * 16;
  *(u32x4*)&t[r][cc] = *(const u32x4*)(src + (size_t)r * srcld + cc);
  *(u32x4*)&t[r][cc + 8] = *(const u32x4*)(src + (size_t)r * srcld + cc + 8);
  __syncthreads();
  __hip_bfloat16 tmp[16] __attribute__((aligned(16)));
#pragma unroll
  for (int k2 = 0; k2 < 16; ++k2) tmp[k2] = t[cc + k2][r];
  *(u32x4*)(dst + (size_t)r * SEQ + cc) = *(u32x4*)&tmp[0];
  *(u32x4*)(dst + (size_t)r * SEQ + cc + 8) = *(u32x4*)&tmp[8];
}

// ---------------- chunk-local end state ----------------
__global__ __launch_bounds__(256, 2) void state_gemm(const __hip_bfloat16* __restrict__ XdT,
                                                     const __hip_bfloat16* __restrict__ Bt,
                                                     const float* __restrict__ scum, float* __restrict__ cstat) {
  __shared__ __align__(16) __hip_bfloat16 Xw[64 * 136];
  __shared__ __align__(16) __hip_bfloat16 Bts[128 * 136];
  __shared__ float rS[CHUNK];
  int bid = blockIdx.x;
  int c = bid & 15, bh = bid >> 4;
  int b = bh / NHEADS, h = bh % NHEADS;
  const float* sp = scum + ((size_t)(b * NCHUNK + c) * NHEADS + h) * CHUNK;
  int tid = threadIdx.x;
  if (tid < CHUNK) rS[tid] = __expf(sp[CHUNK - 1] - sp[tid]);
  {
    int n = tid >> 1, jc = (tid & 1) * 64;
    const __hip_bfloat16* g = Bt + ((size_t)(b * DSTATE + n)) * SEQ + c * CHUNK + jc;
#pragma unroll
    for (int q = 0; q < 8; ++q) *(u32x4*)&Bts[n * 136 + jc + q * 8] = *(const u32x4*)(g + q * 8);
  }
  __syncthreads();
  {
    int p = tid >> 2, jc = (tid & 3) * 32;
    const __hip_bfloat16* g = XdT + ((size_t)((b * NHEADS + h) * 64 + p)) * SEQ + c * CHUNK + jc;
#pragma unroll
    for (int q = 0; q < 4; ++q) {
      bf16x8 vv = *(const bf16x8*)(g + q * 8);
      bf16x8 ov;
#pragma unroll
      for (int e = 0; e < 8; ++e) ov[e] = (__bf16)((float)vv[e] * rS[jc + q * 8 + e]);
      *(bf16x8*)&Xw[p * 136 + jc + q * 8] = ov;
    }
  }
  __syncthreads();
  const int lane = tid & 63, wid = tid >> 6;
  const int wm = wid >> 1, wn = wid & 1;
  const int lr = lane & 15, lk = lane >> 4;
  f32x4 acc[2][4] = {};
#pragma unroll
  for (int ks = 0; ks < 4; ++ks) {
    bf16x8 af[2], bq[4];
#pragma unroll
    for (int i = 0; i < 2; ++i) af[i] = *(const bf16x8*)&Xw[(wm * 32 + i * 16 + lr) * 136 + ks * 32 + lk * 8];
#pragma unroll
    for (int j = 0; j < 4; ++j) bq[j] = *(const bf16x8*)&Bts[(wn * 64 + j * 16 + lr) * 136 + ks * 32 + lk * 8];
#pragma unroll
    for (int i = 0; i < 2; ++i)
#pragma unroll
      for (int j = 0; j < 4; ++j)
        acc[i][j] = __builtin_amdgcn_mfma_f32_16x16x32_bf16(af[i], bq[j], acc[i][j], 0, 0, 0);
  }
  float* dst = cstat + (size_t)bid * 8192;
#pragma unroll
  for (int i = 0; i < 2; ++i)
#pragma unroll
    for (int j = 0; j < 4; ++j)
#pragma unroll
      for (int r = 0; r < 4; ++r)
        dst[(wm * 32 + i * 16 + lk * 4 + r) * 128 + wn * 64 + j * 16 + lr] = acc[i][j][r];
}

// ---------------- inter-chunk recurrence (8-way sliced for parallelism) ----------------
__global__ __launch_bounds__(256) void scanB(float* __restrict__ cstat, const float* __restrict__ cdec) {
  const int bh = blockIdx.x >> 3, sl = blockIdx.x & 7;
  const int base = sl * 1024 + threadIdx.x * 4;
  float hreg[4];
#pragma unroll
  for (int j = 0; j < 4; ++j) hreg[j] = 0.f;
  for (int c = 0; c < NCHUNK; ++c) {
    float* p = cstat + (size_t)(bh * NCHUNK + c) * 8192 + base;
    const float P = cdec[bh * NCHUNK + c];
    f32x4 tmp = *(const f32x4*)p;
    f32x4 hs = {hreg[0], hreg[1], hreg[2], hreg[3]};
    *(f32x4*)p = hs;
#pragma unroll
    for (int j = 0; j < 4; ++j) hreg[j] = fmaf(hreg[j], P, tmp[j]);
  }
}

// ---------------- SSD y kernel ----------------
template <int JE>
__global__ __launch_bounds__(256, 2) void ssd_y(const __hip_bfloat16* __restrict__ Cb,
                                                const __hip_bfloat16* __restrict__ Bb,
                                                const __hip_bfloat16* __restrict__ XdT,
                                                const __hip_bfloat16* __restrict__ Xd,
                                                const float* __restrict__ cstat, const float* __restrict__ scum,
                                                const float* __restrict__ dtS, const float* __restrict__ Dvec,
                                                float* __restrict__ zxb) {
  constexpr int HI = JE - 64;
  constexpr int JW = JE / 2;
  constexpr int FJ = JW / 16;
  constexpr int KJ = JE / 32;
  __shared__ __align__(16) __hip_bfloat16 Cs[64 * 136];
  __shared__ __align__(16) __hip_bfloat16 Bs[JE * 136];
  __shared__ __align__(16) __hip_bfloat16 R3[64 * 136];
  __shared__ float sS[CHUNK];
  int bid = blockIdx.x;
  int c = bid & 15, bh = bid >> 4;
  int b = bh / NHEADS, h = bh % NHEADS;
  int m0 = b * SEQ + c * CHUNK;
  int tid = threadIdx.x;
  const float* sp = scum + ((size_t)(b * NCHUNK + c) * NHEADS + h) * CHUNK;
  if (tid < CHUNK) sS[tid] = sp[tid];
  {
    int r = tid >> 2, nc = (tid & 3) * 32;
    const __hip_bfloat16* g = Cb + (size_t)(m0 + HI + r) * DSTATE + nc;
#pragma unroll
    for (int q = 0; q < 4; ++q) *(u32x4*)&Cs[r * 136 + nc + q * 8] = *(const u32x4*)(g + q * 8);
  }
  if (JE == 64) {
    int r = tid >> 2, nc = (tid & 3) * 32;
    const __hip_bfloat16* g = Bb + (size_t)(m0 + r) * DSTATE + nc;
#pragma unroll
    for (int q = 0; q < 4; ++q) *(u32x4*)&Bs[r * 136 + nc + q * 8] = *(const u32x4*)(g + q * 8);
  } else {
    int r = tid >> 1, nc = (tid & 1) * 64;
    const __hip_bfloat16* g = Bb + (size_t)(m0 + r) * DSTATE + nc;
#pragma unroll
    for (int q = 0; q < 8; ++q) *(u32x4*)&Bs[r * 136 + nc + q * 8] = *(const u32x4*)(g + q * 8);
  }
  {
    int p = tid >> 2, nc = (tid & 3) * 32;
    const float* g = cstat + (size_t)bid * 8192 + p * 128 + nc;
#pragma unroll
    for (int q = 0; q < 4; ++q) {
      f32x4 v0 = *(const f32x4*)(g + q * 8);
      f32x4 v1 = *(const f32x4*)(g + q * 8 + 4);
      bf16x8 ov;
      ov[0] = (__bf16)v0[0]; ov[1] = (__bf16)v0[1]; ov[2] = (__bf16)v0[2]; ov[3] = (__bf16)v0[3];
      ov[4] = (__bf16)v1[0]; ov[5] = (__bf16)v1[1]; ov[6] = (__bf16)v1[2]; ov[7] = (__bf16)v1[3];
      *(bf16x8*)&R3[p * 136 + nc + q * 8] = ov;
    }
  }
  __syncthreads();
  const int lane = tid & 63, wid = tid >> 6;
  const int wm = wid >> 1, wn = wid & 1;
  const int lr = lane & 15, lk = lane >> 4;
  f32x4 Gacc[2][FJ] = {};
  f32x4 Uacc[2][2] = {};
#pragma unroll
  for (int ks = 0; ks < 4; ++ks) {
    bf16x8 af[2], bq[2];
#pragma unroll
    for (int i = 0; i < 2; ++i) af[i] = *(const bf16x8*)&Cs[(wm * 32 + i * 16 + lr) * 136 + ks * 32 + lk * 8];
#pragma unroll
    for (int j = 0; j < 2; ++j) bq[j] = *(const bf16x8*)&R3[(wn * 32 + j * 16 + lr) * 136 + ks * 32 + lk * 8];
#pragma unroll
    for (int i = 0; i < 2; ++i)
#pragma unroll
      for (int j = 0; j < 2; ++j)
        Uacc[i][j] = __builtin_amdgcn_mfma_f32_16x16x32_bf16(af[i], bq[j], Uacc[i][j], 0, 0, 0);
  }
#pragma unroll
  for (int ks = 0; ks < 4; ++ks) {
    bf16x8 af[2], bq[FJ];
#pragma unroll
    for (int i = 0; i < 2; ++i) af[i] = *(const bf16x8*)&Cs[(wm * 32 + i * 16 + lr) * 136 + ks * 32 + lk * 8];
#pragma unroll
    for (int j = 0; j < FJ; ++j) bq[j] = *(const bf16x8*)&Bs[(wn * JW + j * 16 + lr) * 136 + ks * 32 + lk * 8];
#pragma unroll
    for (int i = 0; i < 2; ++i)
#pragma unroll
      for (int j = 0; j < FJ; ++j)
        Gacc[i][j] = __builtin_amdgcn_mfma_f32_16x16x32_bf16(af[i], bq[j], Gacc[i][j], 0, 0, 0);
  }
  __syncthreads();
  {
    float siv[2][4];
#pragma unroll
    for (int i = 0; i < 2; ++i)
#pragma unroll
      for (int r = 0; r < 4; ++r) siv[i][r] = sS[HI + wm * 32 + i * 16 + lk * 4 + r];
#pragma unroll
    for (int i = 0; i < 2; ++i)
#pragma unroll
      for (int j = 0; j < FJ; ++j) {
        int gj = wn * JW + j * 16 + lr;
        float sj = sS[gj];
#pragma unroll
        for (int r = 0; r < 4; ++r) {
          int il = wm * 32 + i * 16 + lk * 4 + r;
          int gi = HI + il;
          float mv = (gj <= gi) ? Gacc[i][j][r] * __expf(siv[i][r] - sj) : 0.f;
          Cs[il * 136 + gj] = __float2bfloat16(mv);
        }
      }
  }
  {
    int p = tid >> 2, jc = (tid & 3) * (JE / 4);
    const __hip_bfloat16* g = XdT + ((size_t)((b * NHEADS + h) * 64 + p)) * SEQ + c * CHUNK + jc;
#pragma unroll
    for (int q = 0; q < JE / 32; ++q) *(u32x4*)&R3[p * 136 + jc + q * 8] = *(const u32x4*)(g + q * 8);
  }
  __syncthreads();
  f32x4 Yacc[2][2] = {};
#pragma unroll
  for (int ks = 0; ks < KJ; ++ks) {
    bf16x8 af[2], bq[2];
#pragma unroll
    for (int i = 0; i < 2; ++i) af[i] = *(const bf16x8*)&Cs[(wm * 32 + i * 16 + lr) * 136 + ks * 32 + lk * 8];
#pragma unroll
    for (int j = 0; j < 2; ++j) bq[j] = *(const bf16x8*)&R3[(wn * 32 + j * 16 + lr) * 136 + ks * 32 + lk * 8];
#pragma unroll
    for (int i = 0; i < 2; ++i)
#pragma unroll
      for (int j = 0; j < 2; ++j)
        Yacc[i][j] = __builtin_amdgcn_mfma_f32_16x16x32_bf16(af[i], bq[j], Yacc[i][j], 0, 0, 0);
  }
  const float Dh = Dvec[h];
#pragma unroll
  for (int i = 0; i < 2; ++i)
#pragma unroll
    for (int r = 0; r < 4; ++r) {
      int il = wm * 32 + i * 16 + lk * 4 + r;
      int gi = HI + il;
      int m = m0 + gi;
      float ei = __expf(sS[gi]);
      float dt = dtS[(size_t)m * NHEADS + h];
#pragma unroll
      for (int j = 0; j < 2; ++j) {
        int p = wn * 32 + j * 16 + lr;
        float xv = (float)Xd[(size_t)m * DINNER + h * 64 + p] / dt;
        zxb[(size_t)m * LDZ + DINNER + h * 64 + p] = Yacc[i][j][r] + ei * Uacc[i][j][r] + Dh * xv;
      }
    }
}

// ---------------- RMSNorm + silu(z) gate -> bf16 ----------------
__global__ __launch_bounds__(256) void norm_gate(const float* __restrict__ zxb, const float* __restrict__ nw,
                                                 __hip_bfloat16* __restrict__ yg) {
  const int m = blockIdx.x, tid = threadIdx.x;
  const float* zr = zxb + (size_t)m * LDZ;
  const float* yr = zr + DINNER;
  float yv[6], zv[6];
  float ss = 0.f;
#pragma unroll
  for (int jj = 0; jj < 6; ++jj) {
    int i = tid + jj * 256;
    yv[jj] = yr[i];
    zv[jj] = zr[i];
    ss = fmaf(yv[jj], yv[jj], ss);
  }
#pragma unroll
  for (int o = 32; o > 0; o >>= 1) ss += __shfl_down(ss, o);
  __shared__ float red[4];
  if ((tid & 63) == 0) red[tid >> 6] = ss;
  __syncthreads();
  float tot = red[0] + red[1] + red[2] + red[3];
  float r = rsqrtf(tot * (1.f / 1536.f) + 1e-5f);
#pragma unroll
  for (int jj = 0; jj < 6; ++jj) {
    int i = tid + jj * 256;
    float z = zv[jj];
    float g = z / (1.f + __expf(-z));
    yg[(size_t)m * DINNER + i] = __float2bfloat16(nw[i] * yv[jj] * r * g);
  }
}

extern "C" void kernel_launch(void* const* d_in, const int* in_sizes, int n_in,
                              void* d_out, int out_size, void* d_ws, size_t ws_size,
                              hipStream_t stream) {
  (void)in_sizes; (void)n_in; (void)out_size; (void)ws_size;
  const float* u       = (const float*)d_in[0];
  const float* W_in    = (const float*)d_in[1];
  const float* conv_w  = (const float*)d_in[2];
  const float* conv_b  = (const float*)d_in[3];
  const float* dt_bias = (const float*)d_in[4];
  const float* A_log   = (const float*)d_in[5];
  const float* Dvec    = (const float*)d_in[6];
  const float* norm_w  = (const float*)d_in[7];
  const float* W_out   = (const float*)d_in[8];
  float* out = (float*)d_out;

  float* zxb   = (float*)d_ws;
  float* cstat = zxb + (size_t)MTOT * LDZ;
  float* dtS   = cstat + (size_t)NBH * NCHUNK * 8192;
  float* dtA   = dtS + (size_t)MTOT * NHEADS;
  float* scum  = dtA + (size_t)MTOT * NHEADS;
  float* cdec  = scum + (size_t)MTOT * NHEADS;
  __hip_bfloat16* ub  = (__hip_bfloat16*)(cdec + NBH * NCHUNK);
  __hip_bfloat16* wib = ub + (size_t)NU;
  __hip_bfloat16* wob = wib + (size_t)NWI;
  __hip_bfloat16* wdh = wob + (size_t)NWO;
  __hip_bfloat16* wdl = wdh + (size_t)NWD;
  __hip_bfloat16* Xd  = wdl + (size_t)NWD;
  __hip_bfloat16* Bb  = Xd + (size_t)MTOT * DINNER;
  __hip_bfloat16* Cb  = Bb + (size_t)MTOT * DSTATE;
  __hip_bfloat16* XdT = Cb + (size_t)MTOT * DSTATE;
  __hip_bfloat16* Bt  = XdT + (size_t)MTOT * DINNER;
  __hip_bfloat16* yg  = Xd;  // alias: Xd dead after ssd_y

  cvt_bf16<<<(NU + NWI + NWO + 2 * NWD + 255) / 256, 256, 0, stream>>>(u, W_in, W_out, ub, wib, wob, wdh, wdl);
  gemm_bt<<<dim3(LDZ / 128, MTOT / 128), 256, 0, stream>>>(ub, wib, zxb, DMODEL, DMODEL, LDZ, DMODEL / 32);
  dt_mfma<<<MTOT / 64, 256, 0, stream>>>(u, wdh, wdl, dt_bias, A_log, dtS, dtA);
  cumsum_kernel<<<64, 256, 0, stream>>>(dtA, scum, cdec);
  conv_prep<<<dim3(CONVDIM / 256, MTOT), 256, 0, stream>>>(zxb, conv_w, conv_b, dtS, Xd, Bb, Cb);
  transp<<<3072 + 256, 256, 0, stream>>>(Xd, Bb, XdT, Bt);
  state_gemm<<<NBH * NCHUNK, 256, 0, stream>>>(XdT, Bt, scum, cstat);
  scanB<<<NBH * 8, 256, 0, stream>>>(cstat, cdec);
  ssd_y<64><<<NBH * NCHUNK, 256, 0, stream>>>(Cb, Bb, XdT, Xd, cstat, scum, dtS, Dvec, zxb);
  ssd_y<128><<<NBH * NCHUNK, 256, 0, stream>>>(Cb, Bb, XdT, Xd, cstat, scum, dtS, Dvec, zxb);
  norm_gate<<<MTOT, 256, 0, stream>>>(zxb, norm_w, yg);
  gemm_bt<<<dim3(DMODEL / 128, MTOT / 128), 256, 0, stream>>>(yg, wob, out, DINNER, DINNER, DMODEL, DINNER / 32);
}

// Round 5
// 350.115 us; speedup vs baseline: 1.7852x; 1.1901x over previous
//
#include <hip/hip_runtime.h>
#include <hip/hip_bf16.h>

typedef __bf16 bf16x8 __attribute__((ext_vector_type(8)));
typedef float f32x4 __attribute__((ext_vector_type(4)));
typedef unsigned int u32x4 __attribute__((ext_vector_type(4)));

#define MTOT    8192
#define DMODEL  768
#define DINNER  1536
#define DSTATE  128
#define NHEADS  24
#define CONVDIM 1792
#define LDZ     3328
#define SEQ     2048
#define CHUNK   128
#define NCHUNK  16
#define NBH     96

#define NU   (MTOT*DMODEL)
#define NWI  (LDZ*DMODEL)
#define NWO  (DMODEL*DINNER)
#define NWD  (32*DMODEL)

// async global->LDS, 16B per lane; LDS dest = wave-uniform base + lane*16
__device__ __forceinline__ void gl2lds16(const __hip_bfloat16* g, __hip_bfloat16* l) {
  __builtin_amdgcn_global_load_lds((const __attribute__((address_space(1))) void*)g,
                                   (__attribute__((address_space(3))) void*)l, 16, 0, 0);
}

// ---------------- f32 -> bf16 conversions (+ padded hi/lo dt weights) ----------------
__global__ __launch_bounds__(256) void cvt_bf16(const float* __restrict__ u, const float* __restrict__ Wi,
                                                const float* __restrict__ Wo,
                                                __hip_bfloat16* __restrict__ ub, __hip_bfloat16* __restrict__ wib,
                                                __hip_bfloat16* __restrict__ wob,
                                                __hip_bfloat16* __restrict__ wdh, __hip_bfloat16* __restrict__ wdl) {
  int i = blockIdx.x * 256 + threadIdx.x;
  if (i < NU) ub[i] = __float2bfloat16(u[i]);
  else if (i < NU + NWI) { int k = i - NU; wib[k] = __float2bfloat16(Wi[k]); }
  else if (i < NU + NWI + NWO) { int k = i - NU - NWI; wob[k] = __float2bfloat16(Wo[k]); }
  else if (i < NU + NWI + NWO + 2 * NWD) {
    int k = i - NU - NWI - NWO;
    int lo = (k >= NWD);
    if (lo) k -= NWD;
    int row = k / DMODEL, col = k - row * DMODEL;
    float w = (row < NHEADS) ? Wi[(size_t)(LDZ + row) * DMODEL + col] : 0.f;
    __hip_bfloat16 h = __float2bfloat16(w);
    if (!lo) wdh[k] = h;
    else wdl[k] = __float2bfloat16(w - __bfloat162float(h));
  }
}

// ---------------- bf16 NT GEMM: 2-phase dbuf + src-preswizzled LDS (conflict-free reads) ----------------
__global__ __launch_bounds__(256, 2) void gemm_bt(const __hip_bfloat16* __restrict__ A,
                                                  const __hip_bfloat16* __restrict__ B,
                                                  float* __restrict__ C, int lda, int ldb, int ldc, int nk) {
  __shared__ __align__(16) __hip_bfloat16 As[2][128 * 32];
  __shared__ __align__(16) __hip_bfloat16 Bs[2][128 * 32];
  const int tid = threadIdx.x;
  const int lane = tid & 63, wid = tid >> 6;
  const int wm = wid >> 1, wn = wid & 1;
  const int bm = blockIdx.y, bn = blockIdx.x;
  // staging: wave wid covers rows wid*32..+31 (two 16-row DMA issues of 1KB each)
  // source chunk pre-swizzled with f(row) = (row>>1)&3 so linear-LDS holds swizzled layout
  const int sr = lane >> 2;                         // row within 16-row issue (issue1 = +16, same f)
  const int sc = (((lane & 3) ^ ((sr >> 1) & 3))) * 8;
  const int row0 = wid * 32 + sr;
  const __hip_bfloat16* Ag0 = A + (size_t)(bm * 128 + row0) * lda + sc;
  const __hip_bfloat16* Ag1 = Ag0 + (size_t)16 * lda;
  const __hip_bfloat16* Bg0 = B + (size_t)(bn * 128 + row0) * ldb + sc;
  const __hip_bfloat16* Bg1 = Bg0 + (size_t)16 * ldb;
  f32x4 acc[4][4] = {};
  const int lr = lane & 15, lk = lane >> 4;
  const int arow = wm * 64 + lr, brow = wn * 64 + lr;
  const int ach = (lk ^ ((lr >> 1) & 3)) * 8;       // read-side swizzled 16B chunk
#define STAGE(buf, ks)                                   \
  do {                                                   \
    gl2lds16(Ag0 + (ks) * 32, &As[buf][(wid * 32) * 32]);      \
    gl2lds16(Ag1 + (ks) * 32, &As[buf][(wid * 32 + 16) * 32]); \
    gl2lds16(Bg0 + (ks) * 32, &Bs[buf][(wid * 32) * 32]);      \
    gl2lds16(Bg1 + (ks) * 32, &Bs[buf][(wid * 32 + 16) * 32]); \
  } while (0)
  STAGE(0, 0);
  __syncthreads();
  for (int ks = 0; ks < nk; ++ks) {
    const int cur = ks & 1;
    if (ks + 1 < nk) STAGE(cur ^ 1, ks + 1);  // issue next tile; latency hides under MFMAs
    bf16x8 af[4], bfr[4];
#pragma unroll
    for (int i = 0; i < 4; ++i) {
      af[i] = *(const bf16x8*)&As[cur][(arow + i * 16) * 32 + ach];
      bfr[i] = *(const bf16x8*)&Bs[cur][(brow + i * 16) * 32 + ach];
    }
#pragma unroll
    for (int i = 0; i < 4; ++i)
#pragma unroll
      for (int j = 0; j < 4; ++j)
        acc[i][j] = __builtin_amdgcn_mfma_f32_16x16x32_bf16(af[i], bfr[j], acc[i][j], 0, 0, 0);
    __syncthreads();  // drains own vmcnt (next tile staged) + joins waves before overwrite
  }
#undef STAGE
  const int crow0 = bm * 128 + wm * 64 + lk * 4;
  const int ccol0 = bn * 128 + wn * 64 + lr;
#pragma unroll
  for (int i = 0; i < 4; ++i)
#pragma unroll
    for (int j = 0; j < 4; ++j)
#pragma unroll
      for (int r = 0; r < 4; ++r)
        C[(size_t)(crow0 + i * 16 + r) * ldc + ccol0 + j * 16] = acc[i][j][r];
}

// ---------------- dt path: split-bf16 MFMA GEMM (fp32-grade) + softplus epilogue ----------------
__global__ __launch_bounds__(256) void dt_mfma(const float* __restrict__ u,
                                               const __hip_bfloat16* __restrict__ wdh,
                                               const __hip_bfloat16* __restrict__ wdl,
                                               const float* __restrict__ dtb, const float* __restrict__ alog,
                                               float* __restrict__ dtS, float* __restrict__ dtA) {
  __shared__ __align__(16) __hip_bfloat16 Uh[64 * 32];
  __shared__ __align__(16) __hip_bfloat16 Ul[64 * 32];
  const int tid = threadIdx.x;
  const int lane = tid & 63, wid = tid >> 6;
  const int lr = lane & 15, lk = lane >> 4;
  const int bm = blockIdx.x;
  const int r = tid >> 2, c0 = (tid & 3) * 8;
  const float* usrc = u + (size_t)(bm * 64 + r) * DMODEL + c0;
  f32x4 acc[2] = {};
  for (int ks = 0; ks < DMODEL / 32; ++ks) {
    float4 v0 = *(const float4*)(usrc + ks * 32);
    float4 v1 = *(const float4*)(usrc + ks * 32 + 4);
    bf16x8 hi, lo;
    const float* vf = (const float*)&v0;
#pragma unroll
    for (int e = 0; e < 4; ++e) {
      __hip_bfloat16 h = __float2bfloat16(vf[e]);
      hi[e] = *(__bf16*)&h;
      __hip_bfloat16 l2 = __float2bfloat16(vf[e] - __bfloat162float(h));
      lo[e] = *(__bf16*)&l2;
    }
    vf = (const float*)&v1;
#pragma unroll
    for (int e = 0; e < 4; ++e) {
      __hip_bfloat16 h = __float2bfloat16(vf[e]);
      hi[4 + e] = *(__bf16*)&h;
      __hip_bfloat16 l2 = __float2bfloat16(vf[e] - __bfloat162float(h));
      lo[4 + e] = *(__bf16*)&l2;
    }
    *(bf16x8*)&Uh[r * 32 + c0] = hi;
    *(bf16x8*)&Ul[r * 32 + c0] = lo;
    __syncthreads();
    bf16x8 ah = *(const bf16x8*)&Uh[(wid * 16 + lr) * 32 + lk * 8];
    bf16x8 al = *(const bf16x8*)&Ul[(wid * 16 + lr) * 32 + lk * 8];
#pragma unroll
    for (int j = 0; j < 2; ++j) {
      bf16x8 bh = *(const bf16x8*)(wdh + (size_t)(j * 16 + lr) * DMODEL + ks * 32 + lk * 8);
      bf16x8 bl = *(const bf16x8*)(wdl + (size_t)(j * 16 + lr) * DMODEL + ks * 32 + lk * 8);
      acc[j] = __builtin_amdgcn_mfma_f32_16x16x32_bf16(ah, bh, acc[j], 0, 0, 0);
      acc[j] = __builtin_amdgcn_mfma_f32_16x16x32_bf16(ah, bl, acc[j], 0, 0, 0);
      acc[j] = __builtin_amdgcn_mfma_f32_16x16x32_bf16(al, bh, acc[j], 0, 0, 0);
    }
    __syncthreads();
  }
#pragma unroll
  for (int j = 0; j < 2; ++j) {
    int col = j * 16 + lr;
    if (col < NHEADS) {
      float nA = -expf(alog[col]);
      float bia = dtb[col];
#pragma unroll
      for (int rr = 0; rr < 4; ++rr) {
        int row = bm * 64 + wid * 16 + lk * 4 + rr;
        float x = acc[j][rr] + bia;
        float dt = (x > 20.f) ? x : log1pf(expf(x));
        dtS[(size_t)row * NHEADS + col] = dt;
        dtA[(size_t)row * NHEADS + col] = nA * dt;
      }
    }
  }
}

// ---------------- per-(b,chunk) cumsum of dt*A over time ----------------
__global__ __launch_bounds__(256) void cumsum_kernel(const float* __restrict__ dtA, float* __restrict__ scum,
                                                     float* __restrict__ cdec) {
  int bc = blockIdx.x;
  int b = bc >> 4, c = bc & 15;
  __shared__ float buf[CHUNK * NHEADS];
  int m0 = b * SEQ + c * CHUNK;
  for (int t = threadIdx.x; t < CHUNK * NHEADS; t += 256)
    buf[t] = dtA[(size_t)m0 * NHEADS + t];
  __syncthreads();
  if (threadIdx.x < NHEADS) {
    int h = threadIdx.x;
    float run = 0.f;
    float* dst = scum + ((size_t)bc * NHEADS + h) * CHUNK;
    for (int j = 0; j < CHUNK; ++j) { run += buf[j * NHEADS + h]; dst[j] = run; }
    cdec[(b * NHEADS + h) * NCHUNK + c] = __expf(run);
  }
}

// ---------------- fused conv + silu + bf16 pack + transpose (Xd,B,C + XdT,Bt) ----------------
// grid (28 ctiles, 128 mtiles); block 256. 64x64 tile; sliding-window causal conv along m.
__global__ __launch_bounds__(256) void conv_fused(const float* __restrict__ zxb, const float* __restrict__ cw,
                                                  const float* __restrict__ cb, const float* __restrict__ dtS,
                                                  __hip_bfloat16* __restrict__ Xd, __hip_bfloat16* __restrict__ Bb,
                                                  __hip_bfloat16* __restrict__ Cb, __hip_bfloat16* __restrict__ XdT,
                                                  __hip_bfloat16* __restrict__ Bt) {
  __shared__ __hip_bfloat16 t[64][72];
  __shared__ float dts_sh[64];
  const int c0 = blockIdx.x * 64, m0 = blockIdx.y * 64;
  const int b = m0 >> 11, l0 = m0 & (SEQ - 1);
  const int tid = threadIdx.x;
  const int c = tid & 63, rg = tid >> 6;  // this thread: col c, rows rg*16..+15
  const int gc = c0 + c;
  const bool isX = (c0 < DINNER);
  if (isX && tid < 64) dts_sh[tid] = dtS[(size_t)(m0 + tid) * NHEADS + (c0 >> 6)];
  const float4 w = *(const float4*)(cw + (size_t)gc * 4);
  const float bias = cb[gc];
  const float* src = zxb + (size_t)(m0 + rg * 16) * LDZ + DINNER + gc;
  const int lbase = l0 + rg * 16;
  float v0 = (lbase >= 3) ? src[-3 * (ptrdiff_t)LDZ] : 0.f;
  float v1 = (lbase >= 2) ? src[-2 * (ptrdiff_t)LDZ] : 0.f;
  float v2 = (lbase >= 1) ? src[-1 * (ptrdiff_t)LDZ] : 0.f;
  __syncthreads();  // dts_sh ready
#pragma unroll
  for (int r = 0; r < 16; ++r) {
    float v3 = src[(ptrdiff_t)r * LDZ];
    float a = bias + v0 * w.x + v1 * w.y + v2 * w.z + v3 * w.w;
    float sv = a / (1.f + __expf(-a));
    int lm = rg * 16 + r;
    __hip_bfloat16 val = __float2bfloat16(isX ? dts_sh[lm] * sv : sv);
    t[lm][c] = val;
    int m = m0 + lm;
    if (isX) Xd[(size_t)m * DINNER + gc] = val;
    else if (gc < DINNER + DSTATE) Bb[(size_t)m * DSTATE + gc - DINNER] = val;
    else Cb[(size_t)m * DSTATE + gc - DINNER - DSTATE] = val;
    v0 = v1; v1 = v2; v2 = v3;
  }
  __syncthreads();
  if (c0 < DINNER + DSTATE) {  // transposed write (Xd and B channels)
    int r2 = tid >> 2, cc = (tid & 3) * 16;
    __hip_bfloat16 tmp[16] __attribute__((aligned(16)));
#pragma unroll
    for (int k = 0; k < 16; ++k) tmp[k] = t[cc + k][r2];
    __hip_bfloat16* dst = isX ? XdT + ((size_t)(b * DINNER + c0 + r2)) * SEQ + l0 + cc
                              : Bt + ((size_t)(b * DSTATE + (c0 - DINNER) + r2)) * SEQ + l0 + cc;
    *(u32x4*)dst = *(u32x4*)&tmp[0];
    *(u32x4*)(dst + 8) = *(u32x4*)&tmp[8];
  }
}

// ---------------- chunk-local end state -> bf16 ----------------
__global__ __launch_bounds__(256, 2) void state_gemm(const __hip_bfloat16* __restrict__ XdT,
                                                     const __hip_bfloat16* __restrict__ Bt,
                                                     const float* __restrict__ scum,
                                                     __hip_bfloat16* __restrict__ cstat) {
  __shared__ __align__(16) __hip_bfloat16 Xw[64 * 136];
  __shared__ __align__(16) __hip_bfloat16 Bts[128 * 136];
  __shared__ float rS[CHUNK];
  int bid = blockIdx.x;
  int c = bid & 15, bh = bid >> 4;
  int b = bh / NHEADS, h = bh % NHEADS;
  const float* sp = scum + ((size_t)(b * NCHUNK + c) * NHEADS + h) * CHUNK;
  int tid = threadIdx.x;
  if (tid < CHUNK) rS[tid] = __expf(sp[CHUNK - 1] - sp[tid]);
  {
    int n = tid >> 1, jc = (tid & 1) * 64;
    const __hip_bfloat16* g = Bt + ((size_t)(b * DSTATE + n)) * SEQ + c * CHUNK + jc;
#pragma unroll
    for (int q = 0; q < 8; ++q) *(u32x4*)&Bts[n * 136 + jc + q * 8] = *(const u32x4*)(g + q * 8);
  }
  __syncthreads();
  {
    int p = tid >> 2, jc = (tid & 3) * 32;
    const __hip_bfloat16* g = XdT + ((size_t)((b * NHEADS + h) * 64 + p)) * SEQ + c * CHUNK + jc;
#pragma unroll
    for (int q = 0; q < 4; ++q) {
      bf16x8 vv = *(const bf16x8*)(g + q * 8);
      bf16x8 ov;
#pragma unroll
      for (int e = 0; e < 8; ++e) ov[e] = (__bf16)((float)vv[e] * rS[jc + q * 8 + e]);
      *(bf16x8*)&Xw[p * 136 + jc + q * 8] = ov;
    }
  }
  __syncthreads();
  const int lane = tid & 63, wid = tid >> 6;
  const int wm = wid >> 1, wn = wid & 1;
  const int lr = lane & 15, lk = lane >> 4;
  f32x4 acc[2][4] = {};
#pragma unroll
  for (int ks = 0; ks < 4; ++ks) {
    bf16x8 af[2], bq[4];
#pragma unroll
    for (int i = 0; i < 2; ++i) af[i] = *(const bf16x8*)&Xw[(wm * 32 + i * 16 + lr) * 136 + ks * 32 + lk * 8];
#pragma unroll
    for (int j = 0; j < 4; ++j) bq[j] = *(const bf16x8*)&Bts[(wn * 64 + j * 16 + lr) * 136 + ks * 32 + lk * 8];
#pragma unroll
    for (int i = 0; i < 2; ++i)
#pragma unroll
      for (int j = 0; j < 4; ++j)
        acc[i][j] = __builtin_amdgcn_mfma_f32_16x16x32_bf16(af[i], bq[j], acc[i][j], 0, 0, 0);
  }
  __hip_bfloat16* dst = cstat + (size_t)bid * 8192;
#pragma unroll
  for (int i = 0; i < 2; ++i)
#pragma unroll
    for (int j = 0; j < 4; ++j)
#pragma unroll
      for (int r = 0; r < 4; ++r)
        dst[(wm * 32 + i * 16 + lk * 4 + r) * 128 + wn * 64 + j * 16 + lr] = __float2bfloat16(acc[i][j][r]);
}

// ---------------- inter-chunk recurrence (bf16 states, f32 accum) ----------------
__global__ __launch_bounds__(256) void scanB(__hip_bfloat16* __restrict__ cstat, const float* __restrict__ cdec) {
  const int bh = blockIdx.x >> 3, sl = blockIdx.x & 7;
  const int base = sl * 1024 + threadIdx.x * 4;
  float hreg[4] = {0.f, 0.f, 0.f, 0.f};
  for (int c = 0; c < NCHUNK; ++c) {
    __hip_bfloat16* p = cstat + (size_t)(bh * NCHUNK + c) * 8192 + base;
    const float P = cdec[bh * NCHUNK + c];
    __hip_bfloat16 tmp[4], hs[4];
    *(uint2*)tmp = *(const uint2*)p;
#pragma unroll
    for (int j = 0; j < 4; ++j) hs[j] = __float2bfloat16(hreg[j]);
    *(uint2*)p = *(uint2*)hs;
#pragma unroll
    for (int j = 0; j < 4; ++j) hreg[j] = fmaf(hreg[j], P, __bfloat162float(tmp[j]));
  }
}

// ---------------- SSD y kernel ----------------
template <int JE>
__global__ __launch_bounds__(256, 2) void ssd_y(const __hip_bfloat16* __restrict__ Cb,
                                                const __hip_bfloat16* __restrict__ Bb,
                                                const __hip_bfloat16* __restrict__ XdT,
                                                const __hip_bfloat16* __restrict__ Xd,
                                                const __hip_bfloat16* __restrict__ cstat,
                                                const float* __restrict__ scum,
                                                const float* __restrict__ dtS, const float* __restrict__ Dvec,
                                                float* __restrict__ zxb) {
  constexpr int HI = JE - 64;
  constexpr int JW = JE / 2;
  constexpr int FJ = JW / 16;
  constexpr int KJ = JE / 32;
  __shared__ __align__(16) __hip_bfloat16 Cs[64 * 136];
  __shared__ __align__(16) __hip_bfloat16 Bs[JE * 136];
  __shared__ __align__(16) __hip_bfloat16 R3[64 * 136];
  __shared__ float sS[CHUNK];
  int bid = blockIdx.x;
  int c = bid & 15, bh = bid >> 4;
  int b = bh / NHEADS, h = bh % NHEADS;
  int m0 = b * SEQ + c * CHUNK;
  int tid = threadIdx.x;
  const float* sp = scum + ((size_t)(b * NCHUNK + c) * NHEADS + h) * CHUNK;
  if (tid < CHUNK) sS[tid] = sp[tid];
  {
    int r = tid >> 2, nc = (tid & 3) * 32;
    const __hip_bfloat16* g = Cb + (size_t)(m0 + HI + r) * DSTATE + nc;
#pragma unroll
    for (int q = 0; q < 4; ++q) *(u32x4*)&Cs[r * 136 + nc + q * 8] = *(const u32x4*)(g + q * 8);
  }
  if (JE == 64) {
    int r = tid >> 2, nc = (tid & 3) * 32;
    const __hip_bfloat16* g = Bb + (size_t)(m0 + r) * DSTATE + nc;
#pragma unroll
    for (int q = 0; q < 4; ++q) *(u32x4*)&Bs[r * 136 + nc + q * 8] = *(const u32x4*)(g + q * 8);
  } else {
    int r = tid >> 1, nc = (tid & 1) * 64;
    const __hip_bfloat16* g = Bb + (size_t)(m0 + r) * DSTATE + nc;
#pragma unroll
    for (int q = 0; q < 8; ++q) *(u32x4*)&Bs[r * 136 + nc + q * 8] = *(const u32x4*)(g + q * 8);
  }
  {  // stage h_startT [64 p][128 n] bf16 direct
    int p = tid >> 2, nc = (tid & 3) * 32;
    const __hip_bfloat16* g = cstat + (size_t)bid * 8192 + p * 128 + nc;
#pragma unroll
    for (int q = 0; q < 4; ++q) *(u32x4*)&R3[p * 136 + nc + q * 8] = *(const u32x4*)(g + q * 8);
  }
  __syncthreads();
  const int lane = tid & 63, wid = tid >> 6;
  const int wm = wid >> 1, wn = wid & 1;
  const int lr = lane & 15, lk = lane >> 4;
  f32x4 Gacc[2][FJ] = {};
  f32x4 Uacc[2][2] = {};
#pragma unroll
  for (int ks = 0; ks < 4; ++ks) {
    bf16x8 af[2], bq[2];
#pragma unroll
    for (int i = 0; i < 2; ++i) af[i] = *(const bf16x8*)&Cs[(wm * 32 + i * 16 + lr) * 136 + ks * 32 + lk * 8];
#pragma unroll
    for (int j = 0; j < 2; ++j) bq[j] = *(const bf16x8*)&R3[(wn * 32 + j * 16 + lr) * 136 + ks * 32 + lk * 8];
#pragma unroll
    for (int i = 0; i < 2; ++i)
#pragma unroll
      for (int j = 0; j < 2; ++j)
        Uacc[i][j] = __builtin_amdgcn_mfma_f32_16x16x32_bf16(af[i], bq[j], Uacc[i][j], 0, 0, 0);
  }
#pragma unroll
  for (int ks = 0; ks < 4; ++ks) {
    bf16x8 af[2], bq[FJ];
#pragma unroll
    for (int i = 0; i < 2; ++i) af[i] = *(const bf16x8*)&Cs[(wm * 32 + i * 16 + lr) * 136 + ks * 32 + lk * 8];
#pragma unroll
    for (int j = 0; j < FJ; ++j) bq[j] = *(const bf16x8*)&Bs[(wn * JW + j * 16 + lr) * 136 + ks * 32 + lk * 8];
#pragma unroll
    for (int i = 0; i < 2; ++i)
#pragma unroll
      for (int j = 0; j < FJ; ++j)
        Gacc[i][j] = __builtin_amdgcn_mfma_f32_16x16x32_bf16(af[i], bq[j], Gacc[i][j], 0, 0, 0);
  }
  __syncthreads();
  {
    float siv[2][4];
#pragma unroll
    for (int i = 0; i < 2; ++i)
#pragma unroll
      for (int r = 0; r < 4; ++r) siv[i][r] = sS[HI + wm * 32 + i * 16 + lk * 4 + r];
#pragma unroll
    for (int i = 0; i < 2; ++i)
#pragma unroll
      for (int j = 0; j < FJ; ++j) {
        int gj = wn * JW + j * 16 + lr;
        float sj = sS[gj];
#pragma unroll
        for (int r = 0; r < 4; ++r) {
          int il = wm * 32 + i * 16 + lk * 4 + r;
          int gi = HI + il;
          float mv = (gj <= gi) ? Gacc[i][j][r] * __expf(siv[i][r] - sj) : 0.f;
          Cs[il * 136 + gj] = __float2bfloat16(mv);
        }
      }
  }
  {
    int p = tid >> 2, jc = (tid & 3) * (JE / 4);
    const __hip_bfloat16* g = XdT + ((size_t)((b * NHEADS + h) * 64 + p)) * SEQ + c * CHUNK + jc;
#pragma unroll
    for (int q = 0; q < JE / 32; ++q) *(u32x4*)&R3[p * 136 + jc + q * 8] = *(const u32x4*)(g + q * 8);
  }
  __syncthreads();
  f32x4 Yacc[2][2] = {};
#pragma unroll
  for (int ks = 0; ks < KJ; ++ks) {
    bf16x8 af[2], bq[2];
#pragma unroll
    for (int i = 0; i < 2; ++i) af[i] = *(const bf16x8*)&Cs[(wm * 32 + i * 16 + lr) * 136 + ks * 32 + lk * 8];
#pragma unroll
    for (int j = 0; j < 2; ++j) bq[j] = *(const bf16x8*)&R3[(wn * 32 + j * 16 + lr) * 136 + ks * 32 + lk * 8];
#pragma unroll
    for (int i = 0; i < 2; ++i)
#pragma unroll
      for (int j = 0; j < 2; ++j)
        Yacc[i][j] = __builtin_amdgcn_mfma_f32_16x16x32_bf16(af[i], bq[j], Yacc[i][j], 0, 0, 0);
  }
  const float Dh = Dvec[h];
#pragma unroll
  for (int i = 0; i < 2; ++i)
#pragma unroll
    for (int r = 0; r < 4; ++r) {
      int il = wm * 32 + i * 16 + lk * 4 + r;
      int gi = HI + il;
      int m = m0 + gi;
      float ei = __expf(sS[gi]);
      float dt = dtS[(size_t)m * NHEADS + h];
#pragma unroll
      for (int j = 0; j < 2; ++j) {
        int p = wn * 32 + j * 16 + lr;
        float xv = (float)Xd[(size_t)m * DINNER + h * 64 + p] / dt;
        zxb[(size_t)m * LDZ + DINNER + h * 64 + p] = Yacc[i][j][r] + ei * Uacc[i][j][r] + Dh * xv;
      }
    }
}

// ---------------- RMSNorm + silu(z) gate -> bf16 ----------------
__global__ __launch_bounds__(256) void norm_gate(const float* __restrict__ zxb, const float* __restrict__ nw,
                                                 __hip_bfloat16* __restrict__ yg) {
  const int m = blockIdx.x, tid = threadIdx.x;
  const float* zr = zxb + (size_t)m * LDZ;
  const float* yr = zr + DINNER;
  float yv[6], zv[6];
  float ss = 0.f;
#pragma unroll
  for (int jj = 0; jj < 6; ++jj) {
    int i = tid + jj * 256;
    yv[jj] = yr[i];
    zv[jj] = zr[i];
    ss = fmaf(yv[jj], yv[jj], ss);
  }
#pragma unroll
  for (int o = 32; o > 0; o >>= 1) ss += __shfl_down(ss, o);
  __shared__ float red[4];
  if ((tid & 63) == 0) red[tid >> 6] = ss;
  __syncthreads();
  float tot = red[0] + red[1] + red[2] + red[3];
  float r = rsqrtf(tot * (1.f / 1536.f) + 1e-5f);
#pragma unroll
  for (int jj = 0; jj < 6; ++jj) {
    int i = tid + jj * 256;
    float z = zv[jj];
    float g = z / (1.f + __expf(-z));
    yg[(size_t)m * DINNER + i] = __float2bfloat16(nw[i] * yv[jj] * r * g);
  }
}

extern "C" void kernel_launch(void* const* d_in, const int* in_sizes, int n_in,
                              void* d_out, int out_size, void* d_ws, size_t ws_size,
                              hipStream_t stream) {
  (void)in_sizes; (void)n_in; (void)out_size; (void)ws_size;
  const float* u       = (const float*)d_in[0];
  const float* W_in    = (const float*)d_in[1];
  const float* conv_w  = (const float*)d_in[2];
  const float* conv_b  = (const float*)d_in[3];
  const float* dt_bias = (const float*)d_in[4];
  const float* A_log   = (const float*)d_in[5];
  const float* Dvec    = (const float*)d_in[6];
  const float* norm_w  = (const float*)d_in[7];
  const float* W_out   = (const float*)d_in[8];
  float* out = (float*)d_out;

  float* zxb = (float*)d_ws;
  __hip_bfloat16* cstatb = (__hip_bfloat16*)(zxb + (size_t)MTOT * LDZ);
  float* dtS  = (float*)(cstatb + (size_t)NBH * NCHUNK * 8192);
  float* dtA  = dtS + (size_t)MTOT * NHEADS;
  float* scum = dtA + (size_t)MTOT * NHEADS;
  float* cdec = scum + (size_t)MTOT * NHEADS;
  __hip_bfloat16* ub  = (__hip_bfloat16*)(cdec + NBH * NCHUNK);
  __hip_bfloat16* wib = ub + (size_t)NU;
  __hip_bfloat16* wob = wib + (size_t)NWI;
  __hip_bfloat16* wdh = wob + (size_t)NWO;
  __hip_bfloat16* wdl = wdh + (size_t)NWD;
  __hip_bfloat16* Xd  = wdl + (size_t)NWD;
  __hip_bfloat16* Bb  = Xd + (size_t)MTOT * DINNER;
  __hip_bfloat16* Cb  = Bb + (size_t)MTOT * DSTATE;
  __hip_bfloat16* XdT = Cb + (size_t)MTOT * DSTATE;
  __hip_bfloat16* Bt  = XdT + (size_t)MTOT * DINNER;
  __hip_bfloat16* yg  = Xd;  // alias: Xd dead after ssd_y

  cvt_bf16<<<(NU + NWI + NWO + 2 * NWD + 255) / 256, 256, 0, stream>>>(u, W_in, W_out, ub, wib, wob, wdh, wdl);
  gemm_bt<<<dim3(LDZ / 128, MTOT / 128), 256, 0, stream>>>(ub, wib, zxb, DMODEL, DMODEL, LDZ, DMODEL / 32);
  dt_mfma<<<MTOT / 64, 256, 0, stream>>>(u, wdh, wdl, dt_bias, A_log, dtS, dtA);
  cumsum_kernel<<<64, 256, 0, stream>>>(dtA, scum, cdec);
  conv_fused<<<dim3(CONVDIM / 64, MTOT / 64), 256, 0, stream>>>(zxb, conv_w, conv_b, dtS, Xd, Bb, Cb, XdT, Bt);
  state_gemm<<<NBH * NCHUNK, 256, 0, stream>>>(XdT, Bt, scum, cstatb);
  scanB<<<NBH * 8, 256, 0, stream>>>(cstatb, cdec);
  ssd_y<64><<<NBH * NCHUNK, 256, 0, stream>>>(Cb, Bb, XdT, Xd, cstatb, scum, dtS, Dvec, zxb);
  ssd_y<128><<<NBH * NCHUNK, 256, 0, stream>>>(Cb, Bb, XdT, Xd, cstatb, scum, dtS, Dvec, zxb);
  norm_gate<<<MTOT, 256, 0, stream>>>(zxb, norm_w, yg);
  gemm_bt<<<dim3(DMODEL / 128, MTOT / 128), 256, 0, stream>>>(yg, wob, out, DINNER, DINNER, DMODEL, DINNER / 32);
}

// Round 6
// 338.231 us; speedup vs baseline: 1.8479x; 1.0351x over previous
//
#include <hip/hip_runtime.h>
#include <hip/hip_bf16.h>

typedef __bf16 bf16x8 __attribute__((ext_vector_type(8)));
typedef float f32x4 __attribute__((ext_vector_type(4)));
typedef unsigned int u32x4 __attribute__((ext_vector_type(4)));

#define MTOT    8192
#define DMODEL  768
#define DINNER  1536
#define DSTATE  128
#define NHEADS  24
#define CONVDIM 1792
#define LDZ     3328
#define SEQ     2048
#define CHUNK   128
#define NCHUNK  16
#define NBH     96

#define NU   (MTOT*DMODEL)
#define NWI  (LDZ*DMODEL)
#define NWO  (DMODEL*DINNER)
#define NWD  (32*DMODEL)

// async global->LDS, 16B per lane; LDS dest = wave-uniform base + lane*16
__device__ __forceinline__ void gl2lds16(const __hip_bfloat16* g, __hip_bfloat16* l) {
  __builtin_amdgcn_global_load_lds((const __attribute__((address_space(1))) void*)g,
                                   (__attribute__((address_space(3))) void*)l, 16, 0, 0);
}

// ---------------- f32 -> bf16 conversions (+ padded hi/lo dt weights) ----------------
__global__ __launch_bounds__(256) void cvt_bf16(const float* __restrict__ u, const float* __restrict__ Wi,
                                                const float* __restrict__ Wo,
                                                __hip_bfloat16* __restrict__ ub, __hip_bfloat16* __restrict__ wib,
                                                __hip_bfloat16* __restrict__ wob,
                                                __hip_bfloat16* __restrict__ wdh, __hip_bfloat16* __restrict__ wdl) {
  int i = blockIdx.x * 256 + threadIdx.x;
  if (i < NU) ub[i] = __float2bfloat16(u[i]);
  else if (i < NU + NWI) { int k = i - NU; wib[k] = __float2bfloat16(Wi[k]); }
  else if (i < NU + NWI + NWO) { int k = i - NU - NWI; wob[k] = __float2bfloat16(Wo[k]); }
  else if (i < NU + NWI + NWO + 2 * NWD) {
    int k = i - NU - NWI - NWO;
    int lo = (k >= NWD);
    if (lo) k -= NWD;
    int row = k / DMODEL, col = k - row * DMODEL;
    float w = (row < NHEADS) ? Wi[(size_t)(LDZ + row) * DMODEL + col] : 0.f;
    __hip_bfloat16 h = __float2bfloat16(w);
    if (!lo) wdh[k] = h;
    else wdl[k] = __float2bfloat16(w - __bfloat162float(h));
  }
}

// ================= 256x256 8-phase bf16 GEMM (T1+T2+T3+T4+T5) =================
// C[m][n] = sum_k A[m][k]*B[n][k].  512 thr, 8 waves 2x4, BK=64, 128KiB LDS dbuf.
// Swizzle: LDS slot (row, pc) holds logical chunk pc ^ (row&7); DMA dest linear,
// global src pre-inverse-swizzled, ds_read applies same XOR (rule #21 involution).
#define BAR256()                          \
  __builtin_amdgcn_sched_barrier(0);      \
  __builtin_amdgcn_s_barrier();           \
  __builtin_amdgcn_sched_barrier(0)

template <typename OutT>
__global__ __launch_bounds__(512, 1) void gemm256(const __hip_bfloat16* __restrict__ A,
                                                  const __hip_bfloat16* __restrict__ B,
                                                  OutT* __restrict__ C, int lda, int ldb, int ldc,
                                                  int nkt, int nbn) {
  __shared__ __align__(16) __hip_bfloat16 As[2][256 * 64];
  __shared__ __align__(16) __hip_bfloat16 Bs[2][256 * 64];
  const int tid = threadIdx.x;
  const int lane = tid & 63, wid = tid >> 6;
  const int wm = wid >> 2, wn = wid & 3;
  const int lr = lane & 15, lk = lane >> 4;
  // T1: bijective XCD swizzle (gridDim.x % 8 == 0)
  const int cpx = (int)gridDim.x >> 3;
  const int swz = ((int)blockIdx.x & 7) * cpx + ((int)blockIdx.x >> 3);
  const int bn = swz % nbn, bm = swz / nbn;
  // staging: slot s = i*512 + tid; row = s>>3, phys chunk = s&7; src chunk = pc ^ (row&7)
  const int srow = tid >> 3;
  const int scol = ((tid & 7) ^ (srow & 7)) * 8;
  const __hip_bfloat16* Ag = A + (size_t)(bm * 256 + srow) * lda + scol;
  const __hip_bfloat16* Bg = B + (size_t)(bn * 256 + srow) * ldb + scol;
  const int ldst = wid * 512;  // wave-uniform LDS elem base (+ i*4096)
  const int rpc = lr & 7;      // read-side row phase (row&7 == lr&7 since frag rows are 16-aligned + lr)

#define STG256(bf, kt, i)                                                             \
  do {                                                                                \
    gl2lds16(Ag + (size_t)(i) * 64 * lda + (size_t)(kt) * 64, &As[bf][(i) * 4096 + ldst]); \
    gl2lds16(Bg + (size_t)(i) * 64 * ldb + (size_t)(kt) * 64, &Bs[bf][(i) * 4096 + ldst]); \
  } while (0)
#define LDA256(bf, mf, ks) (*(const bf16x8*)&As[bf][(wm * 128 + (mf) * 16 + lr) * 64 + (((ks) * 4 + lk) ^ rpc) * 8])
#define LDB256(bf, nf, ks) (*(const bf16x8*)&Bs[bf][(wn * 64 + (nf) * 16 + lr) * 64 + (((ks) * 4 + lk) ^ rpc) * 8])

  f32x4 acc[8][4] = {};
  bf16x8 aF[8], bF0[4], bF1[4];

  // prologue: stage K-tile 0 fully, drain, barrier
  STG256(0, 0, 0); STG256(0, 0, 1); STG256(0, 0, 2); STG256(0, 0, 3);
  asm volatile("s_waitcnt vmcnt(0)" ::: "memory");
  BAR256();

  for (int kt = 0; kt < nkt; ++kt) {
    const int c = kt & 1;
    const bool pf = (kt + 1 < nkt);
    // ---- P0: read A(mh0)+B(nh0); stage half of next tile; MFMA quadrant (mh0,nh0)
#pragma unroll
    for (int i = 0; i < 4; ++i) { aF[i * 2] = LDA256(c, i, 0); aF[i * 2 + 1] = LDA256(c, i, 1); }
#pragma unroll
    for (int j = 0; j < 2; ++j) { bF0[j * 2] = LDB256(c, j, 0); bF0[j * 2 + 1] = LDB256(c, j, 1); }
    if (pf) { STG256(c ^ 1, kt + 1, 0); STG256(c ^ 1, kt + 1, 1); }
    BAR256();
    __builtin_amdgcn_s_setprio(1);
#pragma unroll
    for (int i = 0; i < 4; ++i)
#pragma unroll
      for (int j = 0; j < 2; ++j) {
        acc[i][j] = __builtin_amdgcn_mfma_f32_16x16x32_bf16(aF[i * 2], bF0[j * 2], acc[i][j], 0, 0, 0);
        acc[i][j] = __builtin_amdgcn_mfma_f32_16x16x32_bf16(aF[i * 2 + 1], bF0[j * 2 + 1], acc[i][j], 0, 0, 0);
      }
    __builtin_amdgcn_s_setprio(0);
    BAR256();
    // ---- P1: read B(nh1); stage other half; MFMA (mh0,nh1)
#pragma unroll
    for (int j = 0; j < 2; ++j) { bF1[j * 2] = LDB256(c, 2 + j, 0); bF1[j * 2 + 1] = LDB256(c, 2 + j, 1); }
    if (pf) { STG256(c ^ 1, kt + 1, 2); STG256(c ^ 1, kt + 1, 3); }
    BAR256();
    __builtin_amdgcn_s_setprio(1);
#pragma unroll
    for (int i = 0; i < 4; ++i)
#pragma unroll
      for (int j = 0; j < 2; ++j) {
        acc[i][2 + j] = __builtin_amdgcn_mfma_f32_16x16x32_bf16(aF[i * 2], bF1[j * 2], acc[i][2 + j], 0, 0, 0);
        acc[i][2 + j] = __builtin_amdgcn_mfma_f32_16x16x32_bf16(aF[i * 2 + 1], bF1[j * 2 + 1], acc[i][2 + j], 0, 0, 0);
      }
    __builtin_amdgcn_s_setprio(0);
    BAR256();
    // ---- P2: read A(mh1); MFMA (mh1,nh1)
#pragma unroll
    for (int i = 0; i < 4; ++i) { aF[i * 2] = LDA256(c, 4 + i, 0); aF[i * 2 + 1] = LDA256(c, 4 + i, 1); }
    BAR256();
    __builtin_amdgcn_s_setprio(1);
#pragma unroll
    for (int i = 0; i < 4; ++i)
#pragma unroll
      for (int j = 0; j < 2; ++j) {
        acc[4 + i][2 + j] = __builtin_amdgcn_mfma_f32_16x16x32_bf16(aF[i * 2], bF1[j * 2], acc[4 + i][2 + j], 0, 0, 0);
        acc[4 + i][2 + j] = __builtin_amdgcn_mfma_f32_16x16x32_bf16(aF[i * 2 + 1], bF1[j * 2 + 1], acc[4 + i][2 + j], 0, 0, 0);
      }
    __builtin_amdgcn_s_setprio(0);
    BAR256();
    // ---- P3: MFMA (mh1,nh0); counted boundary wait (loads issued 2-3 phases ago)
    __builtin_amdgcn_s_setprio(1);
#pragma unroll
    for (int i = 0; i < 4; ++i)
#pragma unroll
      for (int j = 0; j < 2; ++j) {
        acc[4 + i][j] = __builtin_amdgcn_mfma_f32_16x16x32_bf16(aF[i * 2], bF0[j * 2], acc[4 + i][j], 0, 0, 0);
        acc[4 + i][j] = __builtin_amdgcn_mfma_f32_16x16x32_bf16(aF[i * 2 + 1], bF0[j * 2 + 1], acc[4 + i][j], 0, 0, 0);
      }
    __builtin_amdgcn_s_setprio(0);
    if (pf) { asm volatile("s_waitcnt vmcnt(0)" ::: "memory"); }
    BAR256();
  }
#undef STG256
#undef LDA256
#undef LDB256
  const int crow0 = bm * 256 + wm * 128 + lk * 4;
  const int ccol0 = bn * 256 + wn * 64 + lr;
#pragma unroll
  for (int mf = 0; mf < 8; ++mf)
#pragma unroll
    for (int nf = 0; nf < 4; ++nf)
#pragma unroll
      for (int r = 0; r < 4; ++r)
        C[(size_t)(crow0 + mf * 16 + r) * ldc + ccol0 + nf * 16] = (OutT)acc[mf][nf][r];
}

// ---------------- bf16 NT GEMM 128^2 2-phase (kept for out-projection, f32 C) ----------------
__global__ __launch_bounds__(256, 2) void gemm_bt(const __hip_bfloat16* __restrict__ A,
                                                  const __hip_bfloat16* __restrict__ B,
                                                  float* __restrict__ C, int lda, int ldb, int ldc, int nk) {
  __shared__ __align__(16) __hip_bfloat16 As[2][128 * 32];
  __shared__ __align__(16) __hip_bfloat16 Bs[2][128 * 32];
  const int tid = threadIdx.x;
  const int lane = tid & 63, wid = tid >> 6;
  const int wm = wid >> 1, wn = wid & 1;
  const int bm = blockIdx.y, bn = blockIdx.x;
  const int sr = lane >> 2;
  const int sc = (((lane & 3) ^ ((sr >> 1) & 3))) * 8;
  const int row0 = wid * 32 + sr;
  const __hip_bfloat16* Ag0 = A + (size_t)(bm * 128 + row0) * lda + sc;
  const __hip_bfloat16* Ag1 = Ag0 + (size_t)16 * lda;
  const __hip_bfloat16* Bg0 = B + (size_t)(bn * 128 + row0) * ldb + sc;
  const __hip_bfloat16* Bg1 = Bg0 + (size_t)16 * ldb;
  f32x4 acc[4][4] = {};
  const int lr = lane & 15, lk = lane >> 4;
  const int arow = wm * 64 + lr, brow = wn * 64 + lr;
  const int ach = (lk ^ ((lr >> 1) & 3)) * 8;
#define STAGE(buf, ks)                                         \
  do {                                                         \
    gl2lds16(Ag0 + (ks) * 32, &As[buf][(wid * 32) * 32]);      \
    gl2lds16(Ag1 + (ks) * 32, &As[buf][(wid * 32 + 16) * 32]); \
    gl2lds16(Bg0 + (ks) * 32, &Bs[buf][(wid * 32) * 32]);      \
    gl2lds16(Bg1 + (ks) * 32, &Bs[buf][(wid * 32 + 16) * 32]); \
  } while (0)
  STAGE(0, 0);
  __syncthreads();
  for (int ks = 0; ks < nk; ++ks) {
    const int cur = ks & 1;
    if (ks + 1 < nk) STAGE(cur ^ 1, ks + 1);
    bf16x8 af[4], bfr[4];
#pragma unroll
    for (int i = 0; i < 4; ++i) {
      af[i] = *(const bf16x8*)&As[cur][(arow + i * 16) * 32 + ach];
      bfr[i] = *(const bf16x8*)&Bs[cur][(brow + i * 16) * 32 + ach];
    }
#pragma unroll
    for (int i = 0; i < 4; ++i)
#pragma unroll
      for (int j = 0; j < 4; ++j)
        acc[i][j] = __builtin_amdgcn_mfma_f32_16x16x32_bf16(af[i], bfr[j], acc[i][j], 0, 0, 0);
    __syncthreads();
  }
#undef STAGE
  const int crow0 = bm * 128 + wm * 64 + lk * 4;
  const int ccol0 = bn * 128 + wn * 64 + lr;
#pragma unroll
  for (int i = 0; i < 4; ++i)
#pragma unroll
    for (int j = 0; j < 4; ++j)
#pragma unroll
      for (int r = 0; r < 4; ++r)
        C[(size_t)(crow0 + i * 16 + r) * ldc + ccol0 + j * 16] = acc[i][j][r];
}

// ---------------- dt path: split-bf16 MFMA GEMM (fp32-grade) + softplus epilogue ----------------
__global__ __launch_bounds__(256) void dt_mfma(const float* __restrict__ u,
                                               const __hip_bfloat16* __restrict__ wdh,
                                               const __hip_bfloat16* __restrict__ wdl,
                                               const float* __restrict__ dtb, const float* __restrict__ alog,
                                               float* __restrict__ dtS, float* __restrict__ dtA) {
  __shared__ __align__(16) __hip_bfloat16 Uh[64 * 32];
  __shared__ __align__(16) __hip_bfloat16 Ul[64 * 32];
  const int tid = threadIdx.x;
  const int lane = tid & 63, wid = tid >> 6;
  const int lr = lane & 15, lk = lane >> 4;
  const int bm = blockIdx.x;
  const int r = tid >> 2, c0 = (tid & 3) * 8;
  const float* usrc = u + (size_t)(bm * 64 + r) * DMODEL + c0;
  f32x4 acc[2] = {};
  for (int ks = 0; ks < DMODEL / 32; ++ks) {
    float4 v0 = *(const float4*)(usrc + ks * 32);
    float4 v1 = *(const float4*)(usrc + ks * 32 + 4);
    bf16x8 hi, lo;
    const float* vf = (const float*)&v0;
#pragma unroll
    for (int e = 0; e < 4; ++e) {
      __hip_bfloat16 h = __float2bfloat16(vf[e]);
      hi[e] = *(__bf16*)&h;
      __hip_bfloat16 l2 = __float2bfloat16(vf[e] - __bfloat162float(h));
      lo[e] = *(__bf16*)&l2;
    }
    vf = (const float*)&v1;
#pragma unroll
    for (int e = 0; e < 4; ++e) {
      __hip_bfloat16 h = __float2bfloat16(vf[e]);
      hi[4 + e] = *(__bf16*)&h;
      __hip_bfloat16 l2 = __float2bfloat16(vf[e] - __bfloat162float(h));
      lo[4 + e] = *(__bf16*)&l2;
    }
    *(bf16x8*)&Uh[r * 32 + c0] = hi;
    *(bf16x8*)&Ul[r * 32 + c0] = lo;
    __syncthreads();
    bf16x8 ah = *(const bf16x8*)&Uh[(wid * 16 + lr) * 32 + lk * 8];
    bf16x8 al = *(const bf16x8*)&Ul[(wid * 16 + lr) * 32 + lk * 8];
#pragma unroll
    for (int j = 0; j < 2; ++j) {
      bf16x8 bh = *(const bf16x8*)(wdh + (size_t)(j * 16 + lr) * DMODEL + ks * 32 + lk * 8);
      bf16x8 bl = *(const bf16x8*)(wdl + (size_t)(j * 16 + lr) * DMODEL + ks * 32 + lk * 8);
      acc[j] = __builtin_amdgcn_mfma_f32_16x16x32_bf16(ah, bh, acc[j], 0, 0, 0);
      acc[j] = __builtin_amdgcn_mfma_f32_16x16x32_bf16(ah, bl, acc[j], 0, 0, 0);
      acc[j] = __builtin_amdgcn_mfma_f32_16x16x32_bf16(al, bh, acc[j], 0, 0, 0);
    }
    __syncthreads();
  }
#pragma unroll
  for (int j = 0; j < 2; ++j) {
    int col = j * 16 + lr;
    if (col < NHEADS) {
      float nA = -expf(alog[col]);
      float bia = dtb[col];
#pragma unroll
      for (int rr = 0; rr < 4; ++rr) {
        int row = bm * 64 + wid * 16 + lk * 4 + rr;
        float x = acc[j][rr] + bia;
        float dt = (x > 20.f) ? x : log1pf(expf(x));
        dtS[(size_t)row * NHEADS + col] = dt;
        dtA[(size_t)row * NHEADS + col] = nA * dt;
      }
    }
  }
}

// ---------------- per-(b,chunk) cumsum of dt*A over time ----------------
__global__ __launch_bounds__(256) void cumsum_kernel(const float* __restrict__ dtA, float* __restrict__ scum,
                                                     float* __restrict__ cdec) {
  int bc = blockIdx.x;
  int b = bc >> 4, c = bc & 15;
  __shared__ float buf[CHUNK * NHEADS];
  int m0 = b * SEQ + c * CHUNK;
  for (int t = threadIdx.x; t < CHUNK * NHEADS; t += 256)
    buf[t] = dtA[(size_t)m0 * NHEADS + t];
  __syncthreads();
  if (threadIdx.x < NHEADS) {
    int h = threadIdx.x;
    float run = 0.f;
    float* dst = scum + ((size_t)bc * NHEADS + h) * CHUNK;
    for (int j = 0; j < CHUNK; ++j) { run += buf[j * NHEADS + h]; dst[j] = run; }
    cdec[(b * NHEADS + h) * NCHUNK + c] = __expf(run);
  }
}

// ---------------- fused conv + silu + bf16 pack + transpose (reads bf16 zxb) ----------------
__global__ __launch_bounds__(256) void conv_fused(const __hip_bfloat16* __restrict__ zxb,
                                                  const float* __restrict__ cw,
                                                  const float* __restrict__ cb, const float* __restrict__ dtS,
                                                  __hip_bfloat16* __restrict__ Xd, __hip_bfloat16* __restrict__ Bb,
                                                  __hip_bfloat16* __restrict__ Cb, __hip_bfloat16* __restrict__ XdT,
                                                  __hip_bfloat16* __restrict__ Bt) {
  __shared__ __hip_bfloat16 t[64][72];
  __shared__ float dts_sh[64];
  const int c0 = blockIdx.x * 64, m0 = blockIdx.y * 64;
  const int b = m0 >> 11, l0 = m0 & (SEQ - 1);
  const int tid = threadIdx.x;
  const int c = tid & 63, rg = tid >> 6;
  const int gc = c0 + c;
  const bool isX = (c0 < DINNER);
  if (isX && tid < 64) dts_sh[tid] = dtS[(size_t)(m0 + tid) * NHEADS + (c0 >> 6)];
  const float4 w = *(const float4*)(cw + (size_t)gc * 4);
  const float bias = cb[gc];
  const __hip_bfloat16* src = zxb + (size_t)(m0 + rg * 16) * LDZ + DINNER + gc;
  const int lbase = l0 + rg * 16;
  float v0 = (lbase >= 3) ? __bfloat162float(src[-3 * (ptrdiff_t)LDZ]) : 0.f;
  float v1 = (lbase >= 2) ? __bfloat162float(src[-2 * (ptrdiff_t)LDZ]) : 0.f;
  float v2 = (lbase >= 1) ? __bfloat162float(src[-1 * (ptrdiff_t)LDZ]) : 0.f;
  __syncthreads();
#pragma unroll
  for (int r = 0; r < 16; ++r) {
    float v3 = __bfloat162float(src[(ptrdiff_t)r * LDZ]);
    float a = bias + v0 * w.x + v1 * w.y + v2 * w.z + v3 * w.w;
    float sv = a / (1.f + __expf(-a));
    int lm = rg * 16 + r;
    __hip_bfloat16 val = __float2bfloat16(isX ? dts_sh[lm] * sv : sv);
    t[lm][c] = val;
    int m = m0 + lm;
    if (isX) Xd[(size_t)m * DINNER + gc] = val;
    else if (gc < DINNER + DSTATE) Bb[(size_t)m * DSTATE + gc - DINNER] = val;
    else Cb[(size_t)m * DSTATE + gc - DINNER - DSTATE] = val;
    v0 = v1; v1 = v2; v2 = v3;
  }
  __syncthreads();
  if (c0 < DINNER + DSTATE) {
    int r2 = tid >> 2, cc = (tid & 3) * 16;
    __hip_bfloat16 tmp[16] __attribute__((aligned(16)));
#pragma unroll
    for (int k = 0; k < 16; ++k) tmp[k] = t[cc + k][r2];
    __hip_bfloat16* dst = isX ? XdT + ((size_t)(b * DINNER + c0 + r2)) * SEQ + l0 + cc
                              : Bt + ((size_t)(b * DSTATE + (c0 - DINNER) + r2)) * SEQ + l0 + cc;
    *(u32x4*)dst = *(u32x4*)&tmp[0];
    *(u32x4*)(dst + 8) = *(u32x4*)&tmp[8];
  }
}

// ---------------- chunk-local end state -> bf16 ----------------
__global__ __launch_bounds__(256, 2) void state_gemm(const __hip_bfloat16* __restrict__ XdT,
                                                     const __hip_bfloat16* __restrict__ Bt,
                                                     const float* __restrict__ scum,
                                                     __hip_bfloat16* __restrict__ cstat) {
  __shared__ __align__(16) __hip_bfloat16 Xw[64 * 136];
  __shared__ __align__(16) __hip_bfloat16 Bts[128 * 136];
  __shared__ float rS[CHUNK];
  int bid = blockIdx.x;
  int c = bid & 15, bh = bid >> 4;
  int b = bh / NHEADS, h = bh % NHEADS;
  const float* sp = scum + ((size_t)(b * NCHUNK + c) * NHEADS + h) * CHUNK;
  int tid = threadIdx.x;
  if (tid < CHUNK) rS[tid] = __expf(sp[CHUNK - 1] - sp[tid]);
  {
    int n = tid >> 1, jc = (tid & 1) * 64;
    const __hip_bfloat16* g = Bt + ((size_t)(b * DSTATE + n)) * SEQ + c * CHUNK + jc;
#pragma unroll
    for (int q = 0; q < 8; ++q) *(u32x4*)&Bts[n * 136 + jc + q * 8] = *(const u32x4*)(g + q * 8);
  }
  __syncthreads();
  {
    int p = tid >> 2, jc = (tid & 3) * 32;
    const __hip_bfloat16* g = XdT + ((size_t)((b * NHEADS + h) * 64 + p)) * SEQ + c * CHUNK + jc;
#pragma unroll
    for (int q = 0; q < 4; ++q) {
      bf16x8 vv = *(const bf16x8*)(g + q * 8);
      bf16x8 ov;
#pragma unroll
      for (int e = 0; e < 8; ++e) ov[e] = (__bf16)((float)vv[e] * rS[jc + q * 8 + e]);
      *(bf16x8*)&Xw[p * 136 + jc + q * 8] = ov;
    }
  }
  __syncthreads();
  const int lane = tid & 63, wid = tid >> 6;
  const int wm = wid >> 1, wn = wid & 1;
  const int lr = lane & 15, lk = lane >> 4;
  f32x4 acc[2][4] = {};
#pragma unroll
  for (int ks = 0; ks < 4; ++ks) {
    bf16x8 af[2], bq[4];
#pragma unroll
    for (int i = 0; i < 2; ++i) af[i] = *(const bf16x8*)&Xw[(wm * 32 + i * 16 + lr) * 136 + ks * 32 + lk * 8];
#pragma unroll
    for (int j = 0; j < 4; ++j) bq[j] = *(const bf16x8*)&Bts[(wn * 64 + j * 16 + lr) * 136 + ks * 32 + lk * 8];
#pragma unroll
    for (int i = 0; i < 2; ++i)
#pragma unroll
      for (int j = 0; j < 4; ++j)
        acc[i][j] = __builtin_amdgcn_mfma_f32_16x16x32_bf16(af[i], bq[j], acc[i][j], 0, 0, 0);
  }
  __hip_bfloat16* dst = cstat + (size_t)bid * 8192;
#pragma unroll
  for (int i = 0; i < 2; ++i)
#pragma unroll
    for (int j = 0; j < 4; ++j)
#pragma unroll
      for (int r = 0; r < 4; ++r)
        dst[(wm * 32 + i * 16 + lk * 4 + r) * 128 + wn * 64 + j * 16 + lr] = __float2bfloat16(acc[i][j][r]);
}

// ---------------- inter-chunk recurrence (bf16 states, f32 accum) ----------------
__global__ __launch_bounds__(256) void scanB(__hip_bfloat16* __restrict__ cstat, const float* __restrict__ cdec) {
  const int bh = blockIdx.x >> 3, sl = blockIdx.x & 7;
  const int base = sl * 1024 + threadIdx.x * 4;
  float hreg[4] = {0.f, 0.f, 0.f, 0.f};
  for (int c = 0; c < NCHUNK; ++c) {
    __hip_bfloat16* p = cstat + (size_t)(bh * NCHUNK + c) * 8192 + base;
    const float P = cdec[bh * NCHUNK + c];
    __hip_bfloat16 tmp[4], hs[4];
    *(uint2*)tmp = *(const uint2*)p;
#pragma unroll
    for (int j = 0; j < 4; ++j) hs[j] = __float2bfloat16(hreg[j]);
    *(uint2*)p = *(uint2*)hs;
#pragma unroll
    for (int j = 0; j < 4; ++j) hreg[j] = fmaf(hreg[j], P, __bfloat162float(tmp[j]));
  }
}

// ---------------- SSD y kernel (y out: bf16 into zxb) ----------------
template <int JE>
__global__ __launch_bounds__(256, 2) void ssd_y(const __hip_bfloat16* __restrict__ Cb,
                                                const __hip_bfloat16* __restrict__ Bb,
                                                const __hip_bfloat16* __restrict__ XdT,
                                                const __hip_bfloat16* __restrict__ Xd,
                                                const __hip_bfloat16* __restrict__ cstat,
                                                const float* __restrict__ scum,
                                                const float* __restrict__ dtS, const float* __restrict__ Dvec,
                                                __hip_bfloat16* __restrict__ zxb) {
  constexpr int HI = JE - 64;
  constexpr int JW = JE / 2;
  constexpr int FJ = JW / 16;
  constexpr int KJ = JE / 32;
  __shared__ __align__(16) __hip_bfloat16 Cs[64 * 136];
  __shared__ __align__(16) __hip_bfloat16 Bs[JE * 136];
  __shared__ __align__(16) __hip_bfloat16 R3[64 * 136];
  __shared__ float sS[CHUNK];
  int bid = blockIdx.x;
  int c = bid & 15, bh = bid >> 4;
  int b = bh / NHEADS, h = bh % NHEADS;
  int m0 = b * SEQ + c * CHUNK;
  int tid = threadIdx.x;
  const float* sp = scum + ((size_t)(b * NCHUNK + c) * NHEADS + h) * CHUNK;
  if (tid < CHUNK) sS[tid] = sp[tid];
  {
    int r = tid >> 2, nc = (tid & 3) * 32;
    const __hip_bfloat16* g = Cb + (size_t)(m0 + HI + r) * DSTATE + nc;
#pragma unroll
    for (int q = 0; q < 4; ++q) *(u32x4*)&Cs[r * 136 + nc + q * 8] = *(const u32x4*)(g + q * 8);
  }
  if (JE == 64) {
    int r = tid >> 2, nc = (tid & 3) * 32;
    const __hip_bfloat16* g = Bb + (size_t)(m0 + r) * DSTATE + nc;
#pragma unroll
    for (int q = 0; q < 4; ++q) *(u32x4*)&Bs[r * 136 + nc + q * 8] = *(const u32x4*)(g + q * 8);
  } else {
    int r = tid >> 1, nc = (tid & 1) * 64;
    const __hip_bfloat16* g = Bb + (size_t)(m0 + r) * DSTATE + nc;
#pragma unroll
    for (int q = 0; q < 8; ++q) *(u32x4*)&Bs[r * 136 + nc + q * 8] = *(const u32x4*)(g + q * 8);
  }
  {
    int p = tid >> 2, nc = (tid & 3) * 32;
    const __hip_bfloat16* g = cstat + (size_t)bid * 8192 + p * 128 + nc;
#pragma unroll
    for (int q = 0; q < 4; ++q) *(u32x4*)&R3[p * 136 + nc + q * 8] = *(const u32x4*)(g + q * 8);
  }
  __syncthreads();
  const int lane = tid & 63, wid = tid >> 6;
  const int wm = wid >> 1, wn = wid & 1;
  const int lr = lane & 15, lk = lane >> 4;
  f32x4 Gacc[2][FJ] = {};
  f32x4 Uacc[2][2] = {};
#pragma unroll
  for (int ks = 0; ks < 4; ++ks) {
    bf16x8 af[2], bq[2];
#pragma unroll
    for (int i = 0; i < 2; ++i) af[i] = *(const bf16x8*)&Cs[(wm * 32 + i * 16 + lr) * 136 + ks * 32 + lk * 8];
#pragma unroll
    for (int j = 0; j < 2; ++j) bq[j] = *(const bf16x8*)&R3[(wn * 32 + j * 16 + lr) * 136 + ks * 32 + lk * 8];
#pragma unroll
    for (int i = 0; i < 2; ++i)
#pragma unroll
      for (int j = 0; j < 2; ++j)
        Uacc[i][j] = __builtin_amdgcn_mfma_f32_16x16x32_bf16(af[i], bq[j], Uacc[i][j], 0, 0, 0);
  }
#pragma unroll
  for (int ks = 0; ks < 4; ++ks) {
    bf16x8 af[2], bq[FJ];
#pragma unroll
    for (int i = 0; i < 2; ++i) af[i] = *(const bf16x8*)&Cs[(wm * 32 + i * 16 + lr) * 136 + ks * 32 + lk * 8];
#pragma unroll
    for (int j = 0; j < FJ; ++j) bq[j] = *(const bf16x8*)&Bs[(wn * JW + j * 16 + lr) * 136 + ks * 32 + lk * 8];
#pragma unroll
    for (int i = 0; i < 2; ++i)
#pragma unroll
      for (int j = 0; j < FJ; ++j)
        Gacc[i][j] = __builtin_amdgcn_mfma_f32_16x16x32_bf16(af[i], bq[j], Gacc[i][j], 0, 0, 0);
  }
  __syncthreads();
  {
    float siv[2][4];
#pragma unroll
    for (int i = 0; i < 2; ++i)
#pragma unroll
      for (int r = 0; r < 4; ++r) siv[i][r] = sS[HI + wm * 32 + i * 16 + lk * 4 + r];
#pragma unroll
    for (int i = 0; i < 2; ++i)
#pragma unroll
      for (int j = 0; j < FJ; ++j) {
        int gj = wn * JW + j * 16 + lr;
        float sj = sS[gj];
#pragma unroll
        for (int r = 0; r < 4; ++r) {
          int il = wm * 32 + i * 16 + lk * 4 + r;
          int gi = HI + il;
          float mv = (gj <= gi) ? Gacc[i][j][r] * __expf(siv[i][r] - sj) : 0.f;
          Cs[il * 136 + gj] = __float2bfloat16(mv);
        }
      }
  }
  {
    int p = tid >> 2, jc = (tid & 3) * (JE / 4);
    const __hip_bfloat16* g = XdT + ((size_t)((b * NHEADS + h) * 64 + p)) * SEQ + c * CHUNK + jc;
#pragma unroll
    for (int q = 0; q < JE / 32; ++q) *(u32x4*)&R3[p * 136 + jc + q * 8] = *(const u32x4*)(g + q * 8);
  }
  __syncthreads();
  f32x4 Yacc[2][2] = {};
#pragma unroll
  for (int ks = 0; ks < KJ; ++ks) {
    bf16x8 af[2], bq[2];
#pragma unroll
    for (int i = 0; i < 2; ++i) af[i] = *(const bf16x8*)&Cs[(wm * 32 + i * 16 + lr) * 136 + ks * 32 + lk * 8];
#pragma unroll
    for (int j = 0; j < 2; ++j) bq[j] = *(const bf16x8*)&R3[(wn * 32 + j * 16 + lr) * 136 + ks * 32 + lk * 8];
#pragma unroll
    for (int i = 0; i < 2; ++i)
#pragma unroll
      for (int j = 0; j < 2; ++j)
        Yacc[i][j] = __builtin_amdgcn_mfma_f32_16x16x32_bf16(af[i], bq[j], Yacc[i][j], 0, 0, 0);
  }
  const float Dh = Dvec[h];
#pragma unroll
  for (int i = 0; i < 2; ++i)
#pragma unroll
    for (int r = 0; r < 4; ++r) {
      int il = wm * 32 + i * 16 + lk * 4 + r;
      int gi = HI + il;
      int m = m0 + gi;
      float ei = __expf(sS[gi]);
      float dt = dtS[(size_t)m * NHEADS + h];
#pragma unroll
      for (int j = 0; j < 2; ++j) {
        int p = wn * 32 + j * 16 + lr;
        float xv = (float)Xd[(size_t)m * DINNER + h * 64 + p] / dt;
        zxb[(size_t)m * LDZ + DINNER + h * 64 + p] =
            __float2bfloat16(Yacc[i][j][r] + ei * Uacc[i][j][r] + Dh * xv);
      }
    }
}

// ---------------- RMSNorm + silu(z) gate (bf16 in) -> bf16 ----------------
__global__ __launch_bounds__(192) void norm_gate(const __hip_bfloat16* __restrict__ zxb,
                                                 const float* __restrict__ nw,
                                                 __hip_bfloat16* __restrict__ yg) {
  const int m = blockIdx.x, tid = threadIdx.x;
  const __hip_bfloat16* zr = zxb + (size_t)m * LDZ;
  const __hip_bfloat16* yr = zr + DINNER;
  bf16x8 y8 = *(const bf16x8*)&yr[tid * 8];
  bf16x8 z8 = *(const bf16x8*)&zr[tid * 8];
  float yv[8], zv[8];
  float ss = 0.f;
#pragma unroll
  for (int e = 0; e < 8; ++e) {
    yv[e] = (float)y8[e];
    zv[e] = (float)z8[e];
    ss = fmaf(yv[e], yv[e], ss);
  }
#pragma unroll
  for (int o = 32; o > 0; o >>= 1) ss += __shfl_down(ss, o);
  __shared__ float red[3];
  if ((tid & 63) == 0) red[tid >> 6] = ss;
  __syncthreads();
  float tot = red[0] + red[1] + red[2];
  float r = rsqrtf(tot * (1.f / 1536.f) + 1e-5f);
  float4 w0 = *(const float4*)&nw[tid * 8];
  float4 w1 = *(const float4*)&nw[tid * 8 + 4];
  const float* wf = (const float*)&w0;
  bf16x8 o8;
#pragma unroll
  for (int e = 0; e < 8; ++e) {
    float wv = (e < 4) ? wf[e] : ((const float*)&w1)[e - 4];
    float g = zv[e] / (1.f + __expf(-zv[e]));
    o8[e] = (__bf16)(wv * yv[e] * r * g);
  }
  *(bf16x8*)&yg[(size_t)m * DINNER + tid * 8] = o8;
}

extern "C" void kernel_launch(void* const* d_in, const int* in_sizes, int n_in,
                              void* d_out, int out_size, void* d_ws, size_t ws_size,
                              hipStream_t stream) {
  (void)in_sizes; (void)n_in; (void)out_size; (void)ws_size;
  const float* u       = (const float*)d_in[0];
  const float* W_in    = (const float*)d_in[1];
  const float* conv_w  = (const float*)d_in[2];
  const float* conv_b  = (const float*)d_in[3];
  const float* dt_bias = (const float*)d_in[4];
  const float* A_log   = (const float*)d_in[5];
  const float* Dvec    = (const float*)d_in[6];
  const float* norm_w  = (const float*)d_in[7];
  const float* W_out   = (const float*)d_in[8];
  float* out = (float*)d_out;

  __hip_bfloat16* zxbb = (__hip_bfloat16*)d_ws;                       // [8192][3328] bf16
  __hip_bfloat16* cstatb = zxbb + (size_t)MTOT * LDZ;                 // [1536][8192] bf16
  float* dtS  = (float*)(cstatb + (size_t)NBH * NCHUNK * 8192);
  float* dtA  = dtS + (size_t)MTOT * NHEADS;
  float* scum = dtA + (size_t)MTOT * NHEADS;
  float* cdec = scum + (size_t)MTOT * NHEADS;
  __hip_bfloat16* ub  = (__hip_bfloat16*)(cdec + NBH * NCHUNK);
  __hip_bfloat16* wib = ub + (size_t)NU;
  __hip_bfloat16* wob = wib + (size_t)NWI;
  __hip_bfloat16* wdh = wob + (size_t)NWO;
  __hip_bfloat16* wdl = wdh + (size_t)NWD;
  __hip_bfloat16* Xd  = wdl + (size_t)NWD;
  __hip_bfloat16* Bb  = Xd + (size_t)MTOT * DINNER;
  __hip_bfloat16* Cb  = Bb + (size_t)MTOT * DSTATE;
  __hip_bfloat16* XdT = Cb + (size_t)MTOT * DSTATE;
  __hip_bfloat16* Bt  = XdT + (size_t)MTOT * DINNER;
  __hip_bfloat16* yg  = Xd;  // alias: Xd dead after ssd_y

  cvt_bf16<<<(NU + NWI + NWO + 2 * NWD + 255) / 256, 256, 0, stream>>>(u, W_in, W_out, ub, wib, wob, wdh, wdl);
  gemm256<__hip_bfloat16><<<(LDZ / 256) * (MTOT / 256), 512, 0, stream>>>(ub, wib, zxbb, DMODEL, DMODEL, LDZ,
                                                                          DMODEL / 64, LDZ / 256);
  dt_mfma<<<MTOT / 64, 256, 0, stream>>>(u, wdh, wdl, dt_bias, A_log, dtS, dtA);
  cumsum_kernel<<<64, 256, 0, stream>>>(dtA, scum, cdec);
  conv_fused<<<dim3(CONVDIM / 64, MTOT / 64), 256, 0, stream>>>(zxbb, conv_w, conv_b, dtS, Xd, Bb, Cb, XdT, Bt);
  state_gemm<<<NBH * NCHUNK, 256, 0, stream>>>(XdT, Bt, scum, cstatb);
  scanB<<<NBH * 8, 256, 0, stream>>>(cstatb, cdec);
  ssd_y<64><<<NBH * NCHUNK, 256, 0, stream>>>(Cb, Bb, XdT, Xd, cstatb, scum, dtS, Dvec, zxbb);
  ssd_y<128><<<NBH * NCHUNK, 256, 0, stream>>>(Cb, Bb, XdT, Xd, cstatb, scum, dtS, Dvec, zxbb);
  norm_gate<<<MTOT, 192, 0, stream>>>(zxbb, norm_w, yg);
  gemm_bt<<<dim3(DMODEL / 128, MTOT / 128), 256, 0, stream>>>(yg, wob, out, DINNER, DINNER, DMODEL, DINNER / 32);
}